// Round 10
// baseline (22104.807 us; speedup 1.0000x reference)
//
#include <hip/hip_runtime.h>
#include <stdint.h>

#define B_ 16
#define N_ 4096
#define NPOINT_ 1024
#define NSAMPLE_ 32
#define PPB 32768            // NPOINT_*NSAMPLE_
#define PTOT 524288          // B_*PPB
#define EPS_ 1e-5f

// ---------- prep: zero stats ----------
__global__ void prep0(float* __restrict__ stats) {
    int i = blockIdx.x * 256 + threadIdx.x;
    if (i < 512) stats[i] = 0.f;
}

// ---------- FPS: fp32 with FMA-contracted distance (XLA CPU codegen form) ----------
__global__ __launch_bounds__(256) void fps_kernel(const float* __restrict__ xyz,
                                                  float* __restrict__ out0) {
    const int b = blockIdx.x;
    const int tid = threadIdx.x;
    const int lane = tid & 63, wid = tid >> 6;
    __shared__ float sx[N_], sy[N_], sz[N_];
    __shared__ float rv[4];
    __shared__ int   ri[4];
    __shared__ int   s_cur;
    const float* xb = xyz + (size_t)b * 3 * N_;
    for (int p = tid; p < N_; p += 256) {
        sx[p] = xb[p]; sy[p] = xb[N_ + p]; sz[p] = xb[2 * N_ + p];
    }
    __syncthreads();
    float px[16], py[16], pz[16], md[16];
#pragma unroll
    for (int j = 0; j < 16; ++j) {
        int p = tid + j * 256;
        px[j] = sx[p]; py[j] = sy[p]; pz[j] = sz[p]; md[j] = 1e10f;
    }
    int cur = 0;
    for (int t = 0; t < NPOINT_; ++t) {
        if (tid == 0) {
            out0[(size_t)b * 3 * NPOINT_ + t]               = sx[cur];
            out0[(size_t)b * 3 * NPOINT_ + NPOINT_ + t]     = sy[cur];
            out0[(size_t)b * 3 * NPOINT_ + 2 * NPOINT_ + t] = sz[cur];
        }
        float cx = sx[cur], cy = sy[cur], cz = sz[cur];
        float bv = -1.f; int bi = 0x7fffffff;
#pragma unroll
        for (int j = 0; j < 16; ++j) {
            float dx = px[j] - cx, dy = py[j] - cy, dz = pz[j] - cz;
            // FMA-contracted: fma(dz,dz, fma(dy,dy, dx*dx))
            float d = __builtin_fmaf(dz, dz, __builtin_fmaf(dy, dy, __fmul_rn(dx, dx)));
            float m = fminf(md[j], d);
            md[j] = m;
            if (m > bv) { bv = m; bi = tid + j * 256; }
        }
#pragma unroll
        for (int off = 32; off >= 1; off >>= 1) {
            float ov = __shfl_down(bv, off);
            int   oi = __shfl_down(bi, off);
            if (ov > bv || (ov == bv && oi < bi)) { bv = ov; bi = oi; }
        }
        if (lane == 0) { rv[wid] = bv; ri[wid] = bi; }
        __syncthreads();
        if (tid == 0) {
            float fv = rv[0]; int fi = ri[0];
#pragma unroll
            for (int w = 1; w < 4; ++w)
                if (rv[w] > fv || (rv[w] == fv && ri[w] < fi)) { fv = rv[w]; fi = ri[w]; }
            s_cur = fi;
        }
        __syncthreads();
        cur = s_cur;
    }
}

// ---------- ball query: fp32, FMA-contracted dot/norms + fma(-2,dot,qs)+ps ----------
__global__ __launch_bounds__(256) void ball_kernel(const float* __restrict__ xyz,
                                                   const float* __restrict__ out0,
                                                   int* __restrict__ ball_idx) {
    int gid  = (blockIdx.x * 256 + threadIdx.x) >> 6;
    int lane = threadIdx.x & 63;
    int b = gid >> 10, s = gid & 1023;
    const float* xb = xyz + (size_t)b * 3 * N_;
    float qx = out0[(size_t)b * 3 * NPOINT_ + s];
    float qy = out0[(size_t)b * 3 * NPOINT_ + NPOINT_ + s];
    float qz = out0[(size_t)b * 3 * NPOINT_ + 2 * NPOINT_ + s];
    float qs = __builtin_fmaf(qz, qz, __builtin_fmaf(qy, qy, __fmul_rn(qx, qx)));
    int cnt = 0, first = 0;
    int* outp = ball_idx + (size_t)gid * NSAMPLE_;
    for (int n0 = 0; n0 < N_; n0 += 64) {
        int n = n0 + lane;
        float px = xb[n], py = xb[N_ + n], pz = xb[2 * N_ + n];
        float dot = __builtin_fmaf(qz, pz, __builtin_fmaf(qy, py, __fmul_rn(qx, px)));
        float ps  = __builtin_fmaf(pz, pz, __builtin_fmaf(py, py, __fmul_rn(px, px)));
        float d   = __fadd_rn(__builtin_fmaf(-2.f, dot, qs), ps);
        bool ok = !(d > 0.04f);
        unsigned long long m = __ballot(ok);
        if (m) {
            if (cnt == 0) first = n0 + (__ffsll((unsigned long long)m) - 1);
            if (ok) {
                int r = __popcll(m & ((1ull << lane) - 1ull));
                int pos = cnt + r;
                if (pos < NSAMPLE_) outp[pos] = n;
            }
            cnt += __popcll(m);
            if (cnt >= NSAMPLE_) break;
        }
    }
    if (cnt < NSAMPLE_) {
        for (int pos = cnt + lane; pos < NSAMPLE_; pos += 64) outp[pos] = first;
    }
}

// ---------- conv1 stats: per-block partial sums of y1, y1^2 ----------
__global__ __launch_bounds__(256) void conv1_stats_kernel(const float* __restrict__ xyz,
                                                          const float* __restrict__ pts,
                                                          const float* __restrict__ out0,
                                                          const int* __restrict__ ball_idx,
                                                          const float* __restrict__ w0,
                                                          const float* __restrict__ b0,
                                                          float* __restrict__ stats1) {
    __shared__ float sw[448];
    __shared__ float lsum[256], lsq[256];
    int tid = threadIdx.x;
    int lane = tid & 63, wid = tid >> 6;
    for (int i = tid; i < 448; i += 256) sw[i] = (i < 384) ? w0[i] : b0[i - 384];
    __syncthreads();
    int p = blockIdx.x * 256 + tid;
    int b = p >> 15, s = (p & 32767) >> 5;
    int gi = ball_idx[p];
    const float* xb = xyz + (size_t)b * 3 * N_;
    const float* pb = pts + (size_t)b * 3 * N_;
    float x0 = xb[gi]          - out0[(size_t)b * 3 * NPOINT_ + s];
    float x1 = xb[N_ + gi]     - out0[(size_t)b * 3 * NPOINT_ + NPOINT_ + s];
    float x2 = xb[2 * N_ + gi] - out0[(size_t)b * 3 * NPOINT_ + 2 * NPOINT_ + s];
    float x3 = pb[gi], x4 = pb[N_ + gi], x5 = pb[2 * N_ + gi];
#pragma unroll
    for (int o = 0; o < 64; ++o) {
        float a = sw[384 + o];
        a += sw[o * 6 + 0] * x0; a += sw[o * 6 + 1] * x1; a += sw[o * 6 + 2] * x2;
        a += sw[o * 6 + 3] * x3; a += sw[o * 6 + 4] * x4; a += sw[o * 6 + 5] * x5;
        float v = a, v2 = a * a;
#pragma unroll
        for (int off = 32; off >= 1; off >>= 1) {
            v  += __shfl_down(v, off);
            v2 += __shfl_down(v2, off);
        }
        if (lane == 0) { lsum[wid * 64 + o] = v; lsq[wid * 64 + o] = v2; }
    }
    __syncthreads();
    if (tid < 64)
        atomicAdd(&stats1[tid * 2], lsum[tid] + lsum[64 + tid] + lsum[128 + tid] + lsum[192 + tid]);
    else if (tid < 128) {
        int c = tid - 64;
        atomicAdd(&stats1[c * 2 + 1], lsq[c] + lsq[64 + c] + lsq[128 + c] + lsq[192 + c]);
    }
}

// ---------- finalize: stats -> scale/shift ----------
__global__ void finalize_small(const float* __restrict__ stats,
                               const float* __restrict__ gamma,
                               const float* __restrict__ beta,
                               float* __restrict__ scale,
                               float* __restrict__ shift, int C) {
    int c = blockIdx.x * 64 + threadIdx.x;
    if (c >= C) return;
    const float inv = 1.f / (float)PTOT;
    float m = stats[c * 2] * inv;
    float v = stats[c * 2 + 1] * inv - m * m;
    float sc = gamma[c] / sqrtf(v + EPS_);
    scale[c] = sc;
    shift[c] = beta[c] - m * sc;
}

// ---------- stats2: recompute conv1+bn1+relu+conv2 per point (all fp32), stats of y2 ----------
__global__ __launch_bounds__(256) void stats2_recompute(const float* __restrict__ xyz,
                                                        const float* __restrict__ pts,
                                                        const float* __restrict__ out0,
                                                        const int* __restrict__ ball_idx,
                                                        const float* __restrict__ w0,
                                                        const float* __restrict__ b0,
                                                        const float* __restrict__ w1,   // [64o][64c]
                                                        const float* __restrict__ b1,
                                                        const float* __restrict__ scale1,
                                                        const float* __restrict__ shift1,
                                                        float* __restrict__ stats2) {
    __shared__ float sw0[448];
    __shared__ float sw1[4096];
    __shared__ float sa[192];
    __shared__ float lsum[256], lsq[256];
    int tid = threadIdx.x, lane = tid & 63, wid = tid >> 6;
    for (int i = tid; i < 448; i += 256) sw0[i] = (i < 384) ? w0[i] : b0[i - 384];
    for (int i = tid; i < 4096; i += 256) sw1[i] = w1[i];
    if (tid < 64) { sa[tid] = scale1[tid]; sa[64 + tid] = shift1[tid]; sa[128 + tid] = b1[tid]; }
    __syncthreads();
    int p = blockIdx.x * 256 + tid;
    int b = p >> 15, s = (p & 32767) >> 5;
    int gi = ball_idx[p];
    const float* xb = xyz + (size_t)b * 3 * N_;
    const float* pb = pts + (size_t)b * 3 * N_;
    float x0 = xb[gi]          - out0[(size_t)b * 3 * NPOINT_ + s];
    float x1 = xb[N_ + gi]     - out0[(size_t)b * 3 * NPOINT_ + NPOINT_ + s];
    float x2 = xb[2 * N_ + gi] - out0[(size_t)b * 3 * NPOINT_ + 2 * NPOINT_ + s];
    float x3 = pb[gi], x4 = pb[N_ + gi], x5 = pb[2 * N_ + gi];
    float xr[64];
#pragma unroll
    for (int c = 0; c < 64; ++c) {
        float a = sw0[384 + c];
        a += sw0[c * 6 + 0] * x0; a += sw0[c * 6 + 1] * x1; a += sw0[c * 6 + 2] * x2;
        a += sw0[c * 6 + 3] * x3; a += sw0[c * 6 + 4] * x4; a += sw0[c * 6 + 5] * x5;
        xr[c] = fmaxf(a * sa[c] + sa[64 + c], 0.f);
    }
    for (int o = 0; o < 64; ++o) {
        float a = sa[128 + o];
#pragma unroll
        for (int c = 0; c < 64; ++c) a += sw1[o * 64 + c] * xr[c];
        float v = a, v2 = a * a;
#pragma unroll
        for (int off = 32; off >= 1; off >>= 1) {
            v  += __shfl_down(v, off);
            v2 += __shfl_down(v2, off);
        }
        if (lane == 0) { lsum[wid * 64 + o] = v; lsq[wid * 64 + o] = v2; }
    }
    __syncthreads();
    if (tid < 64)
        atomicAdd(&stats2[tid * 2], lsum[tid] + lsum[64 + tid] + lsum[128 + tid] + lsum[192 + tid]);
    else if (tid < 128) {
        int c = tid - 64;
        atomicAdd(&stats2[c * 2 + 1], lsq[c] + lsq[64 + c] + lsq[128 + c] + lsq[192 + c]);
    }
}

// ---------- stats3: recompute through conv3 per point (all fp32), stats of y3 ----------
__global__ __launch_bounds__(256) void stats3_recompute(const float* __restrict__ xyz,
                                                        const float* __restrict__ pts,
                                                        const float* __restrict__ out0,
                                                        const int* __restrict__ ball_idx,
                                                        const float* __restrict__ w0,
                                                        const float* __restrict__ b0,
                                                        const float* __restrict__ w1,
                                                        const float* __restrict__ b1,
                                                        const float* __restrict__ scale1,
                                                        const float* __restrict__ shift1,
                                                        const float* __restrict__ w2,   // [128o][64c]
                                                        const float* __restrict__ b2,
                                                        const float* __restrict__ scale2,
                                                        const float* __restrict__ shift2,
                                                        float* __restrict__ stats3) {
    __shared__ float sw0[448];
    __shared__ float sw1[4096];
    __shared__ float sw2[8192];
    __shared__ float sa[192];          // scale1, shift1, b1
    __shared__ float sa2[128];         // scale2, shift2
    __shared__ float sb2[128];
    __shared__ float lsA[512], lsQ[512];
    int tid = threadIdx.x, lane = tid & 63, wid = tid >> 6;
    for (int i = tid; i < 448; i += 256) sw0[i] = (i < 384) ? w0[i] : b0[i - 384];
    for (int i = tid; i < 4096; i += 256) sw1[i] = w1[i];
    for (int i = tid; i < 8192; i += 256) sw2[i] = w2[i];
    if (tid < 64) { sa[tid] = scale1[tid]; sa[64 + tid] = shift1[tid]; sa[128 + tid] = b1[tid]; }
    if (tid < 64) { sa2[tid] = scale2[tid]; sa2[64 + tid] = shift2[tid]; }
    if (tid < 128) sb2[tid] = b2[tid];
    __syncthreads();
    int p = blockIdx.x * 256 + tid;
    int b = p >> 15, s = (p & 32767) >> 5;
    int gi = ball_idx[p];
    const float* xb = xyz + (size_t)b * 3 * N_;
    const float* pb = pts + (size_t)b * 3 * N_;
    float x0 = xb[gi]          - out0[(size_t)b * 3 * NPOINT_ + s];
    float x1 = xb[N_ + gi]     - out0[(size_t)b * 3 * NPOINT_ + NPOINT_ + s];
    float x2 = xb[2 * N_ + gi] - out0[(size_t)b * 3 * NPOINT_ + 2 * NPOINT_ + s];
    float x3 = pb[gi], x4 = pb[N_ + gi], x5 = pb[2 * N_ + gi];
    float xr[64];
#pragma unroll
    for (int c = 0; c < 64; ++c) {
        float a = sw0[384 + c];
        a += sw0[c * 6 + 0] * x0; a += sw0[c * 6 + 1] * x1; a += sw0[c * 6 + 2] * x2;
        a += sw0[c * 6 + 3] * x3; a += sw0[c * 6 + 4] * x4; a += sw0[c * 6 + 5] * x5;
        xr[c] = fmaxf(a * sa[c] + sa[64 + c], 0.f);
    }
    float x3n[64];
#pragma unroll
    for (int o = 0; o < 64; ++o) {
        float a = sa[128 + o];
#pragma unroll
        for (int c = 0; c < 64; ++c) a += sw1[o * 64 + c] * xr[c];
        x3n[o] = fmaxf(a * sa2[o] + sa2[64 + o], 0.f);
    }
    for (int o = 0; o < 128; ++o) {
        float a = sb2[o];
#pragma unroll
        for (int c = 0; c < 64; ++c) a += sw2[o * 64 + c] * x3n[c];
        float v = a, v2 = a * a;
#pragma unroll
        for (int off = 32; off >= 1; off >>= 1) {
            v  += __shfl_down(v, off);
            v2 += __shfl_down(v2, off);
        }
        if (lane == 0) { lsA[wid * 128 + o] = v; lsQ[wid * 128 + o] = v2; }
    }
    __syncthreads();
    if (tid < 128) {
        atomicAdd(&stats3[tid * 2], lsA[tid] + lsA[128 + tid] + lsA[256 + tid] + lsA[384 + tid]);
    } else {
        int o = tid - 128;
        atomicAdd(&stats3[o * 2 + 1], lsQ[o] + lsQ[128 + o] + lsQ[256 + o] + lsQ[384 + o]);
    }
}

// ---------- conv3 + bn3 + relu + maxpool: full fp32 recompute, thread per (b,s,32ch) ----------
__global__ __launch_bounds__(256) void conv3max_recompute(const float* __restrict__ xyz,
                                                          const float* __restrict__ pts,
                                                          const float* __restrict__ out0,
                                                          const int* __restrict__ ball_idx,
                                                          const float* __restrict__ w0,
                                                          const float* __restrict__ b0,
                                                          const float* __restrict__ w1,
                                                          const float* __restrict__ b1,
                                                          const float* __restrict__ scale1,
                                                          const float* __restrict__ shift1,
                                                          const float* __restrict__ w2,
                                                          const float* __restrict__ b2,
                                                          const float* __restrict__ scale2,
                                                          const float* __restrict__ shift2,
                                                          const float* __restrict__ scale3,
                                                          const float* __restrict__ shift3,
                                                          float* __restrict__ out1) {
    __shared__ float sw0[448];
    __shared__ float sw1[4096];
    __shared__ float sw2[8192];
    __shared__ float sa[192];
    __shared__ float sa2[128];
    __shared__ float sb2[128], sc3[128], sh3[128];
    int tid = threadIdx.x;
    for (int i = tid; i < 448; i += 256) sw0[i] = (i < 384) ? w0[i] : b0[i - 384];
    for (int i = tid; i < 4096; i += 256) sw1[i] = w1[i];
    for (int i = tid; i < 8192; i += 256) sw2[i] = w2[i];
    if (tid < 64) { sa[tid] = scale1[tid]; sa[64 + tid] = shift1[tid]; sa[128 + tid] = b1[tid]; }
    if (tid < 64) { sa2[tid] = scale2[tid]; sa2[64 + tid] = shift2[tid]; }
    if (tid < 128) { sb2[tid] = b2[tid]; sc3[tid] = scale3[tid]; sh3[tid] = shift3[tid]; }
    __syncthreads();
    int g = blockIdx.x * 256 + tid;       // 65536 threads: (b,s) x 4 channel groups
    int og = g & 3, bs = g >> 2;
    int b = bs >> 10, s = bs & 1023;
    const float* xb = xyz + (size_t)b * 3 * N_;
    const float* pb = pts + (size_t)b * 3 * N_;
    float qx = out0[(size_t)b * 3 * NPOINT_ + s];
    float qy = out0[(size_t)b * 3 * NPOINT_ + NPOINT_ + s];
    float qz = out0[(size_t)b * 3 * NPOINT_ + 2 * NPOINT_ + s];
    float m[32];
#pragma unroll
    for (int i = 0; i < 32; ++i) m[i] = -1e30f;
    for (int k = 0; k < 32; ++k) {
        int p = b * PPB + s * 32 + k;
        int gi = ball_idx[p];
        float x0 = xb[gi] - qx;
        float x1 = xb[N_ + gi] - qy;
        float x2 = xb[2 * N_ + gi] - qz;
        float x3 = pb[gi], x4 = pb[N_ + gi], x5 = pb[2 * N_ + gi];
        float xr[64];
#pragma unroll
        for (int c = 0; c < 64; ++c) {
            float a = sw0[384 + c];
            a += sw0[c * 6 + 0] * x0; a += sw0[c * 6 + 1] * x1; a += sw0[c * 6 + 2] * x2;
            a += sw0[c * 6 + 3] * x3; a += sw0[c * 6 + 4] * x4; a += sw0[c * 6 + 5] * x5;
            xr[c] = fmaxf(a * sa[c] + sa[64 + c], 0.f);
        }
        float x3n[64];
#pragma unroll
        for (int o = 0; o < 64; ++o) {
            float a = sa[128 + o];
#pragma unroll
            for (int c = 0; c < 64; ++c) a += sw1[o * 64 + c] * xr[c];
            x3n[o] = fmaxf(a * sa2[o] + sa2[64 + o], 0.f);
        }
#pragma unroll
        for (int i = 0; i < 32; ++i) {
            int o = og * 32 + i;
            float a = sb2[o];
#pragma unroll
            for (int c = 0; c < 64; ++c) a += sw2[o * 64 + c] * x3n[c];
            m[i] = fmaxf(m[i], a * sc3[o] + sh3[o]);
        }
    }
#pragma unroll
    for (int i = 0; i < 32; ++i)
        out1[(size_t)b * 131072 + (size_t)(og * 32 + i) * 1024 + s] = fmaxf(m[i], 0.f);
}

extern "C" void kernel_launch(void* const* d_in, const int* in_sizes, int n_in,
                              void* d_out, int out_size, void* d_ws, size_t ws_size,
                              hipStream_t stream) {
    (void)in_sizes; (void)n_in; (void)out_size; (void)ws_size;
    const float* xyz    = (const float*)d_in[0];
    const float* pts    = (const float*)d_in[1];
    const float* w0     = (const float*)d_in[2];
    const float* b0     = (const float*)d_in[3];
    const float* gamma0 = (const float*)d_in[4];
    const float* beta0  = (const float*)d_in[5];
    const float* w1     = (const float*)d_in[6];
    const float* b1     = (const float*)d_in[7];
    const float* gamma1 = (const float*)d_in[8];
    const float* beta1  = (const float*)d_in[9];
    const float* w2     = (const float*)d_in[10];
    const float* b2     = (const float*)d_in[11];
    const float* gamma2 = (const float*)d_in[12];
    const float* beta2  = (const float*)d_in[13];

    char* ws = (char*)d_ws;
    int*   ball_idx = (int*)(ws + 0);               // 2 MB
    float* stats    = (float*)(ws + 2097152);       // 512 floats
    float* scsh     = (float*)(ws + 2099200);       // 512 floats

    float* stats1 = stats;           // 64ch (sum,sq interleaved)
    float* stats2 = stats + 128;     // 64ch
    float* stats3 = stats + 256;     // 128ch
    float* scale1 = scsh,       *shift1 = scsh + 64;
    float* scale2 = scsh + 128, *shift2 = scsh + 192;
    float* scale3 = scsh + 256, *shift3 = scsh + 384;

    float* out0 = (float*)d_out;                 // (B,3,NPOINT)
    float* out1 = out0 + B_ * 3 * NPOINT_;       // (B,128,NPOINT)

    hipLaunchKernelGGL(prep0, dim3(2), dim3(256), 0, stream, stats);
    hipLaunchKernelGGL(fps_kernel, dim3(B_), dim3(256), 0, stream, xyz, out0);
    hipLaunchKernelGGL(ball_kernel, dim3(4096), dim3(256), 0, stream, xyz, out0, ball_idx);
    hipLaunchKernelGGL(conv1_stats_kernel, dim3(2048), dim3(256), 0, stream,
                       xyz, pts, out0, ball_idx, w0, b0, stats1);
    hipLaunchKernelGGL(finalize_small, dim3(1), dim3(64), 0, stream,
                       stats1, gamma0, beta0, scale1, shift1, 64);
    hipLaunchKernelGGL(stats2_recompute, dim3(2048), dim3(256), 0, stream,
                       xyz, pts, out0, ball_idx, w0, b0, w1, b1, scale1, shift1, stats2);
    hipLaunchKernelGGL(finalize_small, dim3(1), dim3(64), 0, stream,
                       stats2, gamma1, beta1, scale2, shift2, 64);
    hipLaunchKernelGGL(stats3_recompute, dim3(2048), dim3(256), 0, stream,
                       xyz, pts, out0, ball_idx, w0, b0, w1, b1, scale1, shift1,
                       w2, b2, scale2, shift2, stats3);
    hipLaunchKernelGGL(finalize_small, dim3(2), dim3(64), 0, stream,
                       stats3, gamma2, beta2, scale3, shift3, 128);
    hipLaunchKernelGGL(conv3max_recompute, dim3(256), dim3(256), 0, stream,
                       xyz, pts, out0, ball_idx, w0, b0, w1, b1, scale1, shift1,
                       w2, b2, scale2, shift2, scale3, shift3, out1);
}

// Round 11
// 1922.954 us; speedup vs baseline: 11.4952x; 11.4952x over previous
//
#include <hip/hip_runtime.h>
#include <stdint.h>

#define B_ 16
#define N_ 4096
#define NPOINT_ 1024
#define NSAMPLE_ 32
#define PPB 32768            // NPOINT_*NSAMPLE_
#define PTOT 524288          // B_*PPB
#define EPS_ 1e-5f

// ---------- bf16 helpers ----------
__device__ __forceinline__ float bf2f(unsigned short h) {
    unsigned int u = ((unsigned int)h) << 16;
    float f; __builtin_memcpy(&f, &u, 4); return f;
}
__device__ __forceinline__ unsigned short f2bf(float f) {
    unsigned int u; __builtin_memcpy(&u, &f, 4);
    u = (u + 0x7fffu + ((u >> 16) & 1u)) >> 16;   // RNE
    return (unsigned short)u;
}

// ---------- prep: zero G3/s3, transpose w1,w2 ----------
__global__ __launch_bounds__(256) void prep_kernel(const float* __restrict__ w1,
                                                   const float* __restrict__ w2,
                                                   float* __restrict__ w1t,
                                                   float* __restrict__ w2t,
                                                   float* __restrict__ g3s3) {
    int i = blockIdx.x * 256 + threadIdx.x;   // 32 blocks -> 8192
    if (i < 4160) g3s3[i] = 0.f;
    if (i < 4096) { int o = i >> 6, c = i & 63; w1t[c * 64 + o] = w1[i]; }
    if (i < 8192) { int o = i >> 6, c = i & 63; w2t[c * 128 + o] = w2[i]; }
}

// ---------- FPS: fp32 FMA-contracted (matches np/XLA ref — VERIFIED R10) ----------
__global__ __launch_bounds__(256) void fps_kernel(const float* __restrict__ xyz,
                                                  float* __restrict__ out0) {
    const int b = blockIdx.x;
    const int tid = threadIdx.x;
    const int lane = tid & 63, wid = tid >> 6;
    __shared__ float sx[N_], sy[N_], sz[N_];
    __shared__ float rv[4];
    __shared__ int   ri[4];
    __shared__ int   s_cur;
    const float* xb = xyz + (size_t)b * 3 * N_;
    for (int p = tid; p < N_; p += 256) {
        sx[p] = xb[p]; sy[p] = xb[N_ + p]; sz[p] = xb[2 * N_ + p];
    }
    __syncthreads();
    float px[16], py[16], pz[16], md[16];
#pragma unroll
    for (int j = 0; j < 16; ++j) {
        int p = tid + j * 256;
        px[j] = sx[p]; py[j] = sy[p]; pz[j] = sz[p]; md[j] = 1e10f;
    }
    int cur = 0;
    for (int t = 0; t < NPOINT_; ++t) {
        if (tid == 0) {
            out0[(size_t)b * 3 * NPOINT_ + t]               = sx[cur];
            out0[(size_t)b * 3 * NPOINT_ + NPOINT_ + t]     = sy[cur];
            out0[(size_t)b * 3 * NPOINT_ + 2 * NPOINT_ + t] = sz[cur];
        }
        float cx = sx[cur], cy = sy[cur], cz = sz[cur];
        float bv = -1.f; int bi = 0x7fffffff;
#pragma unroll
        for (int j = 0; j < 16; ++j) {
            float dx = px[j] - cx, dy = py[j] - cy, dz = pz[j] - cz;
            float d = __builtin_fmaf(dz, dz, __builtin_fmaf(dy, dy, __fmul_rn(dx, dx)));
            float m = fminf(md[j], d);
            md[j] = m;
            if (m > bv) { bv = m; bi = tid + j * 256; }
        }
#pragma unroll
        for (int off = 32; off >= 1; off >>= 1) {
            float ov = __shfl_down(bv, off);
            int   oi = __shfl_down(bi, off);
            if (ov > bv || (ov == bv && oi < bi)) { bv = ov; bi = oi; }
        }
        if (lane == 0) { rv[wid] = bv; ri[wid] = bi; }
        __syncthreads();
        if (tid == 0) {
            float fv = rv[0]; int fi = ri[0];
#pragma unroll
            for (int w = 1; w < 4; ++w)
                if (rv[w] > fv || (rv[w] == fv && ri[w] < fi)) { fv = rv[w]; fi = ri[w]; }
            s_cur = fi;
        }
        __syncthreads();
        cur = s_cur;
    }
}

// ---------- ball query: fp32 FMA-contracted (VERIFIED R10) ----------
__global__ __launch_bounds__(256) void ball_kernel(const float* __restrict__ xyz,
                                                   const float* __restrict__ out0,
                                                   int* __restrict__ ball_idx) {
    int gid  = (blockIdx.x * 256 + threadIdx.x) >> 6;
    int lane = threadIdx.x & 63;
    int b = gid >> 10, s = gid & 1023;
    const float* xb = xyz + (size_t)b * 3 * N_;
    float qx = out0[(size_t)b * 3 * NPOINT_ + s];
    float qy = out0[(size_t)b * 3 * NPOINT_ + NPOINT_ + s];
    float qz = out0[(size_t)b * 3 * NPOINT_ + 2 * NPOINT_ + s];
    float qs = __builtin_fmaf(qz, qz, __builtin_fmaf(qy, qy, __fmul_rn(qx, qx)));
    int cnt = 0, first = 0;
    int* outp = ball_idx + (size_t)gid * NSAMPLE_;
    for (int n0 = 0; n0 < N_; n0 += 64) {
        int n = n0 + lane;
        float px = xb[n], py = xb[N_ + n], pz = xb[2 * N_ + n];
        float dot = __builtin_fmaf(qz, pz, __builtin_fmaf(qy, py, __fmul_rn(qx, px)));
        float ps  = __builtin_fmaf(pz, pz, __builtin_fmaf(py, py, __fmul_rn(px, px)));
        float d   = __fadd_rn(__builtin_fmaf(-2.f, dot, qs), ps);
        bool ok = !(d > 0.04f);
        unsigned long long m = __ballot(ok);
        if (m) {
            if (cnt == 0) first = n0 + (__ffsll((unsigned long long)m) - 1);
            if (ok) {
                int r = __popcll(m & ((1ull << lane) - 1ull));
                int pos = cnt + r;
                if (pos < NSAMPLE_) outp[pos] = n;
            }
            cnt += __popcll(m);
            if (cnt >= NSAMPLE_) break;
        }
    }
    if (cnt < NSAMPLE_) {
        for (int pos = cnt + lane; pos < NSAMPLE_; pos += 64) outp[pos] = first;
    }
}

// ---------- conv1 stats: per-block partial sums of y1, y1^2 ----------
__global__ __launch_bounds__(256) void conv1_stats_kernel(const float* __restrict__ xyz,
                                                          const float* __restrict__ pts,
                                                          const float* __restrict__ out0,
                                                          const int* __restrict__ ball_idx,
                                                          const float* __restrict__ w0,
                                                          const float* __restrict__ b0,
                                                          float* __restrict__ partial1) {
    __shared__ float sw[448];
    __shared__ float lsum[256], lsq[256];
    int tid = threadIdx.x;
    int lane = tid & 63, wid = tid >> 6;
    for (int i = tid; i < 448; i += 256) sw[i] = (i < 384) ? w0[i] : b0[i - 384];
    __syncthreads();
    int p = blockIdx.x * 256 + tid;
    int b = p >> 15, s = (p & 32767) >> 5;
    int gi = ball_idx[p];
    const float* xb = xyz + (size_t)b * 3 * N_;
    const float* pb = pts + (size_t)b * 3 * N_;
    float x0 = xb[gi]          - out0[(size_t)b * 3 * NPOINT_ + s];
    float x1 = xb[N_ + gi]     - out0[(size_t)b * 3 * NPOINT_ + NPOINT_ + s];
    float x2 = xb[2 * N_ + gi] - out0[(size_t)b * 3 * NPOINT_ + 2 * NPOINT_ + s];
    float x3 = pb[gi], x4 = pb[N_ + gi], x5 = pb[2 * N_ + gi];
#pragma unroll
    for (int o = 0; o < 64; ++o) {
        float a = sw[384 + o];
        a += sw[o * 6 + 0] * x0; a += sw[o * 6 + 1] * x1; a += sw[o * 6 + 2] * x2;
        a += sw[o * 6 + 3] * x3; a += sw[o * 6 + 4] * x4; a += sw[o * 6 + 5] * x5;
        float v = a, v2 = a * a;
#pragma unroll
        for (int off = 32; off >= 1; off >>= 1) {
            v  += __shfl_down(v, off);
            v2 += __shfl_down(v2, off);
        }
        if (lane == 0) { lsum[wid * 64 + o] = v; lsq[wid * 64 + o] = v2; }
    }
    __syncthreads();
    if (tid < 64)
        partial1[(size_t)blockIdx.x * 128 + tid] =
            lsum[tid] + lsum[64 + tid] + lsum[128 + tid] + lsum[192 + tid];
    else if (tid < 128) {
        int c = tid - 64;
        partial1[(size_t)blockIdx.x * 128 + tid] =
            lsq[c] + lsq[64 + c] + lsq[128 + c] + lsq[192 + c];
    }
}

// ---------- reduce partials -> scale/shift ----------
__global__ __launch_bounds__(256) void reduce_finalize_kernel(const float* __restrict__ partials,
                                                              int nblocks,
                                                              const float* __restrict__ gamma,
                                                              const float* __restrict__ beta,
                                                              float* __restrict__ scale,
                                                              float* __restrict__ shift) {
    int c = blockIdx.x;
    int tid = threadIdx.x, lane = tid & 63, wid = tid >> 6;
    float s1 = 0.f, s2 = 0.f;
    for (int i = tid; i < nblocks; i += 256) {
        s1 += partials[(size_t)i * 128 + c];
        s2 += partials[(size_t)i * 128 + 64 + c];
    }
#pragma unroll
    for (int off = 32; off >= 1; off >>= 1) {
        s1 += __shfl_down(s1, off);
        s2 += __shfl_down(s2, off);
    }
    __shared__ float r1[4], r2[4];
    if (lane == 0) { r1[wid] = s1; r2[wid] = s2; }
    __syncthreads();
    if (tid == 0) {
        float S1 = r1[0] + r1[1] + r1[2] + r1[3];
        float S2 = r2[0] + r2[1] + r2[2] + r2[3];
        const float inv = 1.f / (float)PTOT;
        float m = S1 * inv;
        float v = S2 * inv - m * m;
        float sc = gamma[c] / sqrtf(v + EPS_);
        scale[c] = sc;
        shift[c] = beta[c] - m * sc;
    }
}

// ---------- conv2 fused: recompute conv1+bn1+relu, 64x64 GEMM, stats, store y2 bf16 ----------
__global__ __launch_bounds__(256) void conv2_fused_kernel(const float* __restrict__ xyz,
                                                          const float* __restrict__ pts,
                                                          const float* __restrict__ out0,
                                                          const int* __restrict__ ball_idx,
                                                          const float* __restrict__ w0,
                                                          const float* __restrict__ b0,
                                                          const float* __restrict__ w1t,  // [64c][64o]
                                                          const float* __restrict__ b1,
                                                          const float* __restrict__ scale1,
                                                          const float* __restrict__ shift1,
                                                          unsigned short* __restrict__ y2,
                                                          float* __restrict__ partial2) {
    __shared__ float sw0[448];
    __shared__ float x1s[6 * 64];
    __shared__ float Xs[64 * 64];
    __shared__ float Ws[64 * 64];
    __shared__ float ssc[64], ssh[64], sb1[64];
    __shared__ float lsum[64], lsq[64];
    int tid = threadIdx.x;
    int p0 = blockIdx.x * 64;
    for (int i = tid; i < 448; i += 256) sw0[i] = (i < 384) ? w0[i] : b0[i - 384];
    for (int i = tid; i < 4096; i += 256) Ws[i] = w1t[i];
    if (tid < 64) { ssc[tid] = scale1[tid]; ssh[tid] = shift1[tid]; sb1[tid] = b1[tid]; }
    if (tid < 64) {
        int p = p0 + tid;
        int b = p >> 15, s = (p & 32767) >> 5;
        int gi = ball_idx[p];
        const float* xb = xyz + (size_t)b * 3 * N_;
        const float* pb = pts + (size_t)b * 3 * N_;
        x1s[0 * 64 + tid] = xb[gi]          - out0[(size_t)b * 3 * NPOINT_ + s];
        x1s[1 * 64 + tid] = xb[N_ + gi]     - out0[(size_t)b * 3 * NPOINT_ + NPOINT_ + s];
        x1s[2 * 64 + tid] = xb[2 * N_ + gi] - out0[(size_t)b * 3 * NPOINT_ + 2 * NPOINT_ + s];
        x1s[3 * 64 + tid] = pb[gi];
        x1s[4 * 64 + tid] = pb[N_ + gi];
        x1s[5 * 64 + tid] = pb[2 * N_ + gi];
    }
    __syncthreads();
    // x2 = relu(affine1(conv1(x1)))
    for (int i = tid; i < 4096; i += 256) {
        int c = i >> 6, p = i & 63;
        float a = sw0[384 + c];
        a += sw0[c * 6 + 0] * x1s[p];
        a += sw0[c * 6 + 1] * x1s[64 + p];
        a += sw0[c * 6 + 2] * x1s[128 + p];
        a += sw0[c * 6 + 3] * x1s[192 + p];
        a += sw0[c * 6 + 4] * x1s[256 + p];
        a += sw0[c * 6 + 5] * x1s[320 + p];
        Xs[i] = fmaxf(a * ssc[c] + ssh[c], 0.f);
    }
    __syncthreads();
    int pt = tid & 15, ot = tid >> 4;
    float acc[16];
#pragma unroll
    for (int i = 0; i < 4; ++i) {
        float bv = sb1[ot * 4 + i];
        acc[i * 4 + 0] = bv; acc[i * 4 + 1] = bv; acc[i * 4 + 2] = bv; acc[i * 4 + 3] = bv;
    }
#pragma unroll 4
    for (int c = 0; c < 64; ++c) {
        float4 xv = *(const float4*)&Xs[c * 64 + pt * 4];
        float4 wv = *(const float4*)&Ws[c * 64 + ot * 4];
        acc[0]  += wv.x * xv.x; acc[1]  += wv.x * xv.y; acc[2]  += wv.x * xv.z; acc[3]  += wv.x * xv.w;
        acc[4]  += wv.y * xv.x; acc[5]  += wv.y * xv.y; acc[6]  += wv.y * xv.z; acc[7]  += wv.y * xv.w;
        acc[8]  += wv.z * xv.x; acc[9]  += wv.z * xv.y; acc[10] += wv.z * xv.z; acc[11] += wv.z * xv.w;
        acc[12] += wv.w * xv.x; acc[13] += wv.w * xv.y; acc[14] += wv.w * xv.z; acc[15] += wv.w * xv.w;
    }
    float sA[4], sQ[4];
#pragma unroll
    for (int i = 0; i < 4; ++i) {
        int o = ot * 4 + i;
        ushort4 u;
        u.x = f2bf(acc[i * 4 + 0]); u.y = f2bf(acc[i * 4 + 1]);
        u.z = f2bf(acc[i * 4 + 2]); u.w = f2bf(acc[i * 4 + 3]);
        *(ushort4*)(y2 + (size_t)o * PTOT + p0 + pt * 4) = u;
        sA[i] = acc[i * 4] + acc[i * 4 + 1] + acc[i * 4 + 2] + acc[i * 4 + 3];
        sQ[i] = acc[i * 4] * acc[i * 4] + acc[i * 4 + 1] * acc[i * 4 + 1]
              + acc[i * 4 + 2] * acc[i * 4 + 2] + acc[i * 4 + 3] * acc[i * 4 + 3];
    }
#pragma unroll
    for (int off = 8; off >= 1; off >>= 1) {
#pragma unroll
        for (int i = 0; i < 4; ++i) {
            sA[i] += __shfl_down(sA[i], off);
            sQ[i] += __shfl_down(sQ[i], off);
        }
    }
    if ((tid & 15) == 0) {
#pragma unroll
        for (int i = 0; i < 4; ++i) { lsum[ot * 4 + i] = sA[i]; lsq[ot * 4 + i] = sQ[i]; }
    }
    __syncthreads();
    if (tid < 64) partial2[(size_t)blockIdx.x * 128 + tid] = lsum[tid];
    else if (tid < 128) partial2[(size_t)blockIdx.x * 128 + tid] = lsq[tid - 64];
}

// ---------- gram3: G3 = sum x3 x3^T, s3 = sum x3, x3 = relu(affine2(y2)) ----------
__global__ __launch_bounds__(256) void gram3_kernel(const unsigned short* __restrict__ y2,
                                                    const float* __restrict__ scale2,
                                                    const float* __restrict__ shift2,
                                                    float* __restrict__ G3,
                                                    float* __restrict__ s3) {
    __shared__ __align__(16) float Xst[64 * 68];   // [p][c], stride 68
    __shared__ float ssc[64], ssh[64];
    int tid = threadIdx.x;
    if (tid < 64) { ssc[tid] = scale2[tid]; ssh[tid] = shift2[tid]; }
    int r = tid >> 4, q = tid & 15;
    float g[16];
#pragma unroll
    for (int i = 0; i < 16; ++i) g[i] = 0.f;
    float srow[4] = {0.f, 0.f, 0.f, 0.f};
    int pbase = blockIdx.x * 2048;
    for (int tile = 0; tile < 32; ++tile) {
        __syncthreads();
        int pb = pbase + tile * 64;
        for (int i = tid * 4; i < 4096; i += 1024) {
            int c = i >> 6, p4 = i & 63;
            ushort4 u = *(const ushort4*)(y2 + (size_t)c * PTOT + pb + p4);
            float sc = ssc[c], sh = ssh[c];
            Xst[(p4 + 0) * 68 + c] = fmaxf(bf2f(u.x) * sc + sh, 0.f);
            Xst[(p4 + 1) * 68 + c] = fmaxf(bf2f(u.y) * sc + sh, 0.f);
            Xst[(p4 + 2) * 68 + c] = fmaxf(bf2f(u.z) * sc + sh, 0.f);
            Xst[(p4 + 3) * 68 + c] = fmaxf(bf2f(u.w) * sc + sh, 0.f);
        }
        __syncthreads();
#pragma unroll 4
        for (int p = 0; p < 64; ++p) {
            float4 av = *(const float4*)&Xst[p * 68 + r * 4];
            float4 bv = *(const float4*)&Xst[p * 68 + q * 4];
            g[0]  += av.x * bv.x; g[1]  += av.x * bv.y; g[2]  += av.x * bv.z; g[3]  += av.x * bv.w;
            g[4]  += av.y * bv.x; g[5]  += av.y * bv.y; g[6]  += av.y * bv.z; g[7]  += av.y * bv.w;
            g[8]  += av.z * bv.x; g[9]  += av.z * bv.y; g[10] += av.z * bv.z; g[11] += av.z * bv.w;
            g[12] += av.w * bv.x; g[13] += av.w * bv.y; g[14] += av.w * bv.z; g[15] += av.w * bv.w;
            if (q == 0) { srow[0] += av.x; srow[1] += av.y; srow[2] += av.z; srow[3] += av.w; }
        }
    }
#pragma unroll
    for (int i = 0; i < 4; ++i)
#pragma unroll
        for (int j = 0; j < 4; ++j)
            atomicAdd(&G3[(r * 4 + i) * 64 + q * 4 + j], g[i * 4 + j]);
    if (q == 0) {
#pragma unroll
        for (int i = 0; i < 4; ++i) atomicAdd(&s3[r * 4 + i], srow[i]);
    }
}

// ---------- finalize3: Gram -> scale3/shift3 ----------
__global__ __launch_bounds__(64) void finalize3_kernel(const float* __restrict__ G3,
                                                       const float* __restrict__ s3,
                                                       const float* __restrict__ w2,
                                                       const float* __restrict__ b2,
                                                       const float* __restrict__ gamma,
                                                       const float* __restrict__ beta,
                                                       float* __restrict__ scale,
                                                       float* __restrict__ shift) {
    int o = blockIdx.x * 64 + threadIdx.x;
    const float* wr = w2 + o * 64;
    double ws = 0.0;
    for (int c = 0; c < 64; ++c) ws += (double)wr[c] * (double)s3[c];
    double qf = 0.0;
    for (int i = 0; i < 64; ++i) {
        double ti = 0.0;
        for (int j = 0; j < 64; ++j) ti += (double)G3[i * 64 + j] * (double)wr[j];
        qf += (double)wr[i] * ti;
    }
    const double invP = 1.0 / (double)PTOT;
    double bb = (double)b2[o];
    double mean = ws * invP + bb;
    double ey2 = qf * invP + 2.0 * bb * (ws * invP) + bb * bb;
    double var = ey2 - mean * mean;
    float sc = gamma[o] / sqrtf((float)var + EPS_);
    scale[o] = sc;
    shift[o] = beta[o] - (float)mean * sc;
}

// ---------- conv3 + bn3 + relu + maxpool fused (tiled, bf16 y2 in) ----------
__global__ __launch_bounds__(256) void conv3_maxpool_kernel(const unsigned short* __restrict__ y2,
                                                            const float* __restrict__ w2t,  // [64c][128o]
                                                            const float* __restrict__ b2,
                                                            const float* __restrict__ scale2,
                                                            const float* __restrict__ shift2,
                                                            const float* __restrict__ scale3,
                                                            const float* __restrict__ shift3,
                                                            float* __restrict__ out1) {
    __shared__ float Xs[64 * 64];
    __shared__ float Ws[64 * 128];
    __shared__ float ssc2[64], ssh2[64];
    __shared__ float sb2[128], ssc3[128], ssh3[128];
    __shared__ float gmax[256];   // [2 groups][128 ch]
    int tid = threadIdx.x;
    int p0 = blockIdx.x * 64;
    if (tid < 64) { ssc2[tid] = scale2[tid]; ssh2[tid] = shift2[tid]; }
    for (int i = tid; i < 128; i += 256) { sb2[i] = b2[i]; ssc3[i] = scale3[i]; ssh3[i] = shift3[i]; }
    for (int i = tid; i < 8192; i += 256) Ws[i] = w2t[i];
    __syncthreads();   // order shared setup writes before reads below
    for (int i = tid * 4; i < 4096; i += 1024) {
        int c = i >> 6, pp = i & 63;
        ushort4 u = *(const ushort4*)(y2 + (size_t)c * PTOT + p0 + pp);
        float sc = ssc2[c], sh = ssh2[c];
        float4 x;
        x.x = fmaxf(bf2f(u.x) * sc + sh, 0.f);
        x.y = fmaxf(bf2f(u.y) * sc + sh, 0.f);
        x.z = fmaxf(bf2f(u.z) * sc + sh, 0.f);
        x.w = fmaxf(bf2f(u.w) * sc + sh, 0.f);
        *(float4*)&Xs[i] = x;
    }
    int pt = tid & 15, ot = tid >> 4;
    float acc[32];
#pragma unroll
    for (int i = 0; i < 8; ++i) {
        float bv = sb2[ot * 8 + i];
        acc[i * 4 + 0] = bv; acc[i * 4 + 1] = bv; acc[i * 4 + 2] = bv; acc[i * 4 + 3] = bv;
    }
    __syncthreads();
#pragma unroll 4
    for (int c = 0; c < 64; ++c) {
        float4 xv = *(const float4*)&Xs[c * 64 + pt * 4];
#pragma unroll
        for (int i2 = 0; i2 < 2; ++i2) {
            float4 wv = *(const float4*)&Ws[c * 128 + ot * 8 + i2 * 4];
            float* a = &acc[i2 * 16];
            a[0]  += wv.x * xv.x; a[1]  += wv.x * xv.y; a[2]  += wv.x * xv.z; a[3]  += wv.x * xv.w;
            a[4]  += wv.y * xv.x; a[5]  += wv.y * xv.y; a[6]  += wv.y * xv.z; a[7]  += wv.y * xv.w;
            a[8]  += wv.z * xv.x; a[9]  += wv.z * xv.y; a[10] += wv.z * xv.z; a[11] += wv.z * xv.w;
            a[12] += wv.w * xv.x; a[13] += wv.w * xv.y; a[14] += wv.w * xv.z; a[15] += wv.w * xv.w;
        }
    }
    float mx[8];
#pragma unroll
    for (int i = 0; i < 8; ++i) {
        int o = ot * 8 + i;
        float sc = ssc3[o], sh = ssh3[o];
        float m = acc[i * 4 + 0] * sc + sh;
        m = fmaxf(m, acc[i * 4 + 1] * sc + sh);
        m = fmaxf(m, acc[i * 4 + 2] * sc + sh);
        m = fmaxf(m, acc[i * 4 + 3] * sc + sh);
        mx[i] = m;
    }
#pragma unroll
    for (int off = 4; off >= 1; off >>= 1)
#pragma unroll
        for (int i = 0; i < 8; ++i) mx[i] = fmaxf(mx[i], __shfl_down(mx[i], off));
    if ((pt & 7) == 0) {
        int gph = pt >> 3;
#pragma unroll
        for (int i = 0; i < 8; ++i) gmax[gph * 128 + ot * 8 + i] = fmaxf(mx[i], 0.f);
    }
    __syncthreads();
    int b = p0 >> 15, s0 = (p0 & 32767) >> 5;
    int o = tid >> 1, gph = tid & 1;
    out1[(size_t)b * 131072 + (size_t)o * 1024 + s0 + gph] = gmax[gph * 128 + o];
}

extern "C" void kernel_launch(void* const* d_in, const int* in_sizes, int n_in,
                              void* d_out, int out_size, void* d_ws, size_t ws_size,
                              hipStream_t stream) {
    (void)in_sizes; (void)n_in; (void)out_size; (void)ws_size;
    const float* xyz    = (const float*)d_in[0];
    const float* pts    = (const float*)d_in[1];
    const float* w0     = (const float*)d_in[2];
    const float* b0     = (const float*)d_in[3];
    const float* gamma0 = (const float*)d_in[4];
    const float* beta0  = (const float*)d_in[5];
    const float* w1     = (const float*)d_in[6];
    const float* b1     = (const float*)d_in[7];
    const float* gamma1 = (const float*)d_in[8];
    const float* beta1  = (const float*)d_in[9];
    const float* w2     = (const float*)d_in[10];
    const float* b2     = (const float*)d_in[11];
    const float* gamma2 = (const float*)d_in[12];
    const float* beta2  = (const float*)d_in[13];

    char* ws = (char*)d_ws;
    int*   ball_idx = (int*)(ws + 0);                       // 2 MB
    float* partial1 = (float*)(ws + 2097152);               // 1 MB (2048*128)
    float* partial2 = (float*)(ws + 3145728);               // 4 MB (8192*128)
    float* G3       = (float*)(ws + 7340032);               // 16 KB (+ s3 contiguous)
    float* s3       = (float*)(ws + 7356416);               // 256 B
    float* scsh     = (float*)(ws + 7357440);               // 2 KB
    float* w1t      = (float*)(ws + 7359488);               // 16 KB
    float* w2t      = (float*)(ws + 7375872);               // 32 KB
    unsigned short* y2 = (unsigned short*)(ws + 7408640);   // 64 MB -> total ~71.5 MB

    float* scale1 = scsh,       *shift1 = scsh + 64;
    float* scale2 = scsh + 128, *shift2 = scsh + 192;
    float* scale3 = scsh + 256, *shift3 = scsh + 384;

    float* out0 = (float*)d_out;                 // (B,3,NPOINT)
    float* out1 = out0 + B_ * 3 * NPOINT_;       // (B,128,NPOINT)

    hipLaunchKernelGGL(prep_kernel, dim3(32), dim3(256), 0, stream, w1, w2, w1t, w2t, G3);
    hipLaunchKernelGGL(fps_kernel, dim3(B_), dim3(256), 0, stream, xyz, out0);
    hipLaunchKernelGGL(ball_kernel, dim3(4096), dim3(256), 0, stream, xyz, out0, ball_idx);
    hipLaunchKernelGGL(conv1_stats_kernel, dim3(2048), dim3(256), 0, stream,
                       xyz, pts, out0, ball_idx, w0, b0, partial1);
    hipLaunchKernelGGL(reduce_finalize_kernel, dim3(64), dim3(256), 0, stream,
                       partial1, 2048, gamma0, beta0, scale1, shift1);
    hipLaunchKernelGGL(conv2_fused_kernel, dim3(8192), dim3(256), 0, stream,
                       xyz, pts, out0, ball_idx, w0, b0, w1t, b1, scale1, shift1, y2, partial2);
    hipLaunchKernelGGL(reduce_finalize_kernel, dim3(64), dim3(256), 0, stream,
                       partial2, 8192, gamma1, beta1, scale2, shift2);
    hipLaunchKernelGGL(gram3_kernel, dim3(256), dim3(256), 0, stream, y2, scale2, shift2, G3, s3);
    hipLaunchKernelGGL(finalize3_kernel, dim3(2), dim3(64), 0, stream,
                       G3, s3, w2, b2, gamma2, beta2, scale3, shift3);
    hipLaunchKernelGGL(conv3_maxpool_kernel, dim3(8192), dim3(256), 0, stream,
                       y2, w2t, b2, scale2, shift2, scale3, shift3, out1);
}

// Round 12
// 1500.407 us; speedup vs baseline: 14.7325x; 1.2816x over previous
//
#include <hip/hip_runtime.h>
#include <stdint.h>

#define B_ 16
#define N_ 4096
#define NPOINT_ 1024
#define NSAMPLE_ 32
#define PPB 32768            // NPOINT_*NSAMPLE_
#define PTOT 524288          // B_*PPB
#define EPS_ 1e-5f

// ---------- bf16 helpers ----------
__device__ __forceinline__ float bf2f(unsigned short h) {
    unsigned int u = ((unsigned int)h) << 16;
    float f; __builtin_memcpy(&f, &u, 4); return f;
}
__device__ __forceinline__ unsigned short f2bf(float f) {
    unsigned int u; __builtin_memcpy(&u, &f, 4);
    u = (u + 0x7fffu + ((u >> 16) & 1u)) >> 16;   // RNE
    return (unsigned short)u;
}

// ---------- prep: zero G3/s3, transpose w1,w2 ----------
__global__ __launch_bounds__(256) void prep_kernel(const float* __restrict__ w1,
                                                   const float* __restrict__ w2,
                                                   float* __restrict__ w1t,
                                                   float* __restrict__ w2t,
                                                   float* __restrict__ g3s3) {
    int i = blockIdx.x * 256 + threadIdx.x;   // 32 blocks -> 8192
    if (i < 4160) g3s3[i] = 0.f;
    if (i < 4096) { int o = i >> 6, c = i & 63; w1t[c * 64 + o] = w1[i]; }
    if (i < 8192) { int o = i >> 6, c = i & 63; w2t[c * 128 + o] = w2[i]; }
}

// ---------- FPS: fp32 FMA distances (bit-exact vs R10) with packed-u64 argmax ----------
// Packing: non-negative IEEE floats are order-monotone in their bit pattern, so
// max over (dist_bits<<32 | ~idx) == argmax with first-index tie-break.
// One barrier/iter: per-wave maxes go to parity-double-buffered LDS; all
// threads redundantly reduce the 4 slots (no tid0 serialization, no 2nd barrier).
__global__ __launch_bounds__(256) void fps_kernel(const float* __restrict__ xyz,
                                                  float* __restrict__ out0) {
    const int b = blockIdx.x;
    const int tid = threadIdx.x;
    const int lane = tid & 63, wid = tid >> 6;
    __shared__ float sx[N_], sy[N_], sz[N_];
    __shared__ unsigned long long red[2][4];
    const float* xb = xyz + (size_t)b * 3 * N_;
    for (int p = tid; p < N_; p += 256) {
        sx[p] = xb[p]; sy[p] = xb[N_ + p]; sz[p] = xb[2 * N_ + p];
    }
    __syncthreads();
    float px[16], py[16], pz[16], md[16];
    unsigned int nidx[16];
#pragma unroll
    for (int j = 0; j < 16; ++j) {
        int p = tid + j * 256;
        px[j] = sx[p]; py[j] = sy[p]; pz[j] = sz[p]; md[j] = 1e10f;
        nidx[j] = ~(unsigned int)p;
    }
    int cur = 0;
    for (int t = 0; t < NPOINT_; ++t) {
        if (tid == 0) {
            out0[(size_t)b * 3 * NPOINT_ + t]               = sx[cur];
            out0[(size_t)b * 3 * NPOINT_ + NPOINT_ + t]     = sy[cur];
            out0[(size_t)b * 3 * NPOINT_ + 2 * NPOINT_ + t] = sz[cur];
        }
        float cx = sx[cur], cy = sy[cur], cz = sz[cur];
        unsigned long long best = 0ull;
#pragma unroll
        for (int j = 0; j < 16; ++j) {
            float dx = px[j] - cx, dy = py[j] - cy, dz = pz[j] - cz;
            float d = __builtin_fmaf(dz, dz, __builtin_fmaf(dy, dy, __fmul_rn(dx, dx)));
            float m = fminf(md[j], d);
            md[j] = m;
            unsigned int mb; __builtin_memcpy(&mb, &m, 4);
            unsigned long long pk = ((unsigned long long)mb << 32) | nidx[j];
            best = (pk > best) ? pk : best;
        }
#pragma unroll
        for (int off = 32; off >= 1; off >>= 1) {
            unsigned long long o = __shfl_down(best, off);
            best = (o > best) ? o : best;
        }
        if (lane == 0) red[t & 1][wid] = best;
        __syncthreads();
        unsigned long long m0 = red[t & 1][0], m1 = red[t & 1][1];
        unsigned long long m2 = red[t & 1][2], m3 = red[t & 1][3];
        unsigned long long a = (m0 > m1) ? m0 : m1;
        unsigned long long c = (m2 > m3) ? m2 : m3;
        unsigned long long mm = (a > c) ? a : c;
        cur = (int)(~(unsigned int)mm) & (N_ - 1);
    }
}

// ---------- ball query: fp32 FMA-contracted (VERIFIED R10) ----------
__global__ __launch_bounds__(256) void ball_kernel(const float* __restrict__ xyz,
                                                   const float* __restrict__ out0,
                                                   int* __restrict__ ball_idx) {
    int gid  = (blockIdx.x * 256 + threadIdx.x) >> 6;
    int lane = threadIdx.x & 63;
    int b = gid >> 10, s = gid & 1023;
    const float* xb = xyz + (size_t)b * 3 * N_;
    float qx = out0[(size_t)b * 3 * NPOINT_ + s];
    float qy = out0[(size_t)b * 3 * NPOINT_ + NPOINT_ + s];
    float qz = out0[(size_t)b * 3 * NPOINT_ + 2 * NPOINT_ + s];
    float qs = __builtin_fmaf(qz, qz, __builtin_fmaf(qy, qy, __fmul_rn(qx, qx)));
    int cnt = 0, first = 0;
    int* outp = ball_idx + (size_t)gid * NSAMPLE_;
    for (int n0 = 0; n0 < N_; n0 += 64) {
        int n = n0 + lane;
        float px = xb[n], py = xb[N_ + n], pz = xb[2 * N_ + n];
        float dot = __builtin_fmaf(qz, pz, __builtin_fmaf(qy, py, __fmul_rn(qx, px)));
        float ps  = __builtin_fmaf(pz, pz, __builtin_fmaf(py, py, __fmul_rn(px, px)));
        float d   = __fadd_rn(__builtin_fmaf(-2.f, dot, qs), ps);
        bool ok = !(d > 0.04f);
        unsigned long long m = __ballot(ok);
        if (m) {
            if (cnt == 0) first = n0 + (__ffsll((unsigned long long)m) - 1);
            if (ok) {
                int r = __popcll(m & ((1ull << lane) - 1ull));
                int pos = cnt + r;
                if (pos < NSAMPLE_) outp[pos] = n;
            }
            cnt += __popcll(m);
            if (cnt >= NSAMPLE_) break;
        }
    }
    if (cnt < NSAMPLE_) {
        for (int pos = cnt + lane; pos < NSAMPLE_; pos += 64) outp[pos] = first;
    }
}

// ---------- conv1 stats: per-block partial sums of y1, y1^2 ----------
__global__ __launch_bounds__(256) void conv1_stats_kernel(const float* __restrict__ xyz,
                                                          const float* __restrict__ pts,
                                                          const float* __restrict__ out0,
                                                          const int* __restrict__ ball_idx,
                                                          const float* __restrict__ w0,
                                                          const float* __restrict__ b0,
                                                          float* __restrict__ partial1) {
    __shared__ float sw[448];
    __shared__ float lsum[256], lsq[256];
    int tid = threadIdx.x;
    int lane = tid & 63, wid = tid >> 6;
    for (int i = tid; i < 448; i += 256) sw[i] = (i < 384) ? w0[i] : b0[i - 384];
    __syncthreads();
    int p = blockIdx.x * 256 + tid;
    int b = p >> 15, s = (p & 32767) >> 5;
    int gi = ball_idx[p];
    const float* xb = xyz + (size_t)b * 3 * N_;
    const float* pb = pts + (size_t)b * 3 * N_;
    float x0 = xb[gi]          - out0[(size_t)b * 3 * NPOINT_ + s];
    float x1 = xb[N_ + gi]     - out0[(size_t)b * 3 * NPOINT_ + NPOINT_ + s];
    float x2 = xb[2 * N_ + gi] - out0[(size_t)b * 3 * NPOINT_ + 2 * NPOINT_ + s];
    float x3 = pb[gi], x4 = pb[N_ + gi], x5 = pb[2 * N_ + gi];
#pragma unroll
    for (int o = 0; o < 64; ++o) {
        float a = sw[384 + o];
        a += sw[o * 6 + 0] * x0; a += sw[o * 6 + 1] * x1; a += sw[o * 6 + 2] * x2;
        a += sw[o * 6 + 3] * x3; a += sw[o * 6 + 4] * x4; a += sw[o * 6 + 5] * x5;
        float v = a, v2 = a * a;
#pragma unroll
        for (int off = 32; off >= 1; off >>= 1) {
            v  += __shfl_down(v, off);
            v2 += __shfl_down(v2, off);
        }
        if (lane == 0) { lsum[wid * 64 + o] = v; lsq[wid * 64 + o] = v2; }
    }
    __syncthreads();
    if (tid < 64)
        partial1[(size_t)blockIdx.x * 128 + tid] =
            lsum[tid] + lsum[64 + tid] + lsum[128 + tid] + lsum[192 + tid];
    else if (tid < 128) {
        int c = tid - 64;
        partial1[(size_t)blockIdx.x * 128 + tid] =
            lsq[c] + lsq[64 + c] + lsq[128 + c] + lsq[192 + c];
    }
}

// ---------- reduce partials -> scale/shift ----------
__global__ __launch_bounds__(256) void reduce_finalize_kernel(const float* __restrict__ partials,
                                                              int nblocks,
                                                              const float* __restrict__ gamma,
                                                              const float* __restrict__ beta,
                                                              float* __restrict__ scale,
                                                              float* __restrict__ shift) {
    int c = blockIdx.x;
    int tid = threadIdx.x, lane = tid & 63, wid = tid >> 6;
    float s1 = 0.f, s2 = 0.f;
    for (int i = tid; i < nblocks; i += 256) {
        s1 += partials[(size_t)i * 128 + c];
        s2 += partials[(size_t)i * 128 + 64 + c];
    }
#pragma unroll
    for (int off = 32; off >= 1; off >>= 1) {
        s1 += __shfl_down(s1, off);
        s2 += __shfl_down(s2, off);
    }
    __shared__ float r1[4], r2[4];
    if (lane == 0) { r1[wid] = s1; r2[wid] = s2; }
    __syncthreads();
    if (tid == 0) {
        float S1 = r1[0] + r1[1] + r1[2] + r1[3];
        float S2 = r2[0] + r2[1] + r2[2] + r2[3];
        const float inv = 1.f / (float)PTOT;
        float m = S1 * inv;
        float v = S2 * inv - m * m;
        float sc = gamma[c] / sqrtf(v + EPS_);
        scale[c] = sc;
        shift[c] = beta[c] - m * sc;
    }
}

// ---------- conv2 fused: recompute conv1+bn1+relu, 64x64 GEMM, stats, store y2 bf16 ----------
__global__ __launch_bounds__(256) void conv2_fused_kernel(const float* __restrict__ xyz,
                                                          const float* __restrict__ pts,
                                                          const float* __restrict__ out0,
                                                          const int* __restrict__ ball_idx,
                                                          const float* __restrict__ w0,
                                                          const float* __restrict__ b0,
                                                          const float* __restrict__ w1t,  // [64c][64o]
                                                          const float* __restrict__ b1,
                                                          const float* __restrict__ scale1,
                                                          const float* __restrict__ shift1,
                                                          unsigned short* __restrict__ y2,
                                                          float* __restrict__ partial2) {
    __shared__ float sw0[448];
    __shared__ float x1s[6 * 64];
    __shared__ float Xs[64 * 64];
    __shared__ float Ws[64 * 64];
    __shared__ float ssc[64], ssh[64], sb1[64];
    __shared__ float lsum[64], lsq[64];
    int tid = threadIdx.x;
    int p0 = blockIdx.x * 64;
    for (int i = tid; i < 448; i += 256) sw0[i] = (i < 384) ? w0[i] : b0[i - 384];
    for (int i = tid; i < 4096; i += 256) Ws[i] = w1t[i];
    if (tid < 64) { ssc[tid] = scale1[tid]; ssh[tid] = shift1[tid]; sb1[tid] = b1[tid]; }
    if (tid < 64) {
        int p = p0 + tid;
        int b = p >> 15, s = (p & 32767) >> 5;
        int gi = ball_idx[p];
        const float* xb = xyz + (size_t)b * 3 * N_;
        const float* pb = pts + (size_t)b * 3 * N_;
        x1s[0 * 64 + tid] = xb[gi]          - out0[(size_t)b * 3 * NPOINT_ + s];
        x1s[1 * 64 + tid] = xb[N_ + gi]     - out0[(size_t)b * 3 * NPOINT_ + NPOINT_ + s];
        x1s[2 * 64 + tid] = xb[2 * N_ + gi] - out0[(size_t)b * 3 * NPOINT_ + 2 * NPOINT_ + s];
        x1s[3 * 64 + tid] = pb[gi];
        x1s[4 * 64 + tid] = pb[N_ + gi];
        x1s[5 * 64 + tid] = pb[2 * N_ + gi];
    }
    __syncthreads();
    for (int i = tid; i < 4096; i += 256) {
        int c = i >> 6, p = i & 63;
        float a = sw0[384 + c];
        a += sw0[c * 6 + 0] * x1s[p];
        a += sw0[c * 6 + 1] * x1s[64 + p];
        a += sw0[c * 6 + 2] * x1s[128 + p];
        a += sw0[c * 6 + 3] * x1s[192 + p];
        a += sw0[c * 6 + 4] * x1s[256 + p];
        a += sw0[c * 6 + 5] * x1s[320 + p];
        Xs[i] = fmaxf(a * ssc[c] + ssh[c], 0.f);
    }
    __syncthreads();
    int pt = tid & 15, ot = tid >> 4;
    float acc[16];
#pragma unroll
    for (int i = 0; i < 4; ++i) {
        float bv = sb1[ot * 4 + i];
        acc[i * 4 + 0] = bv; acc[i * 4 + 1] = bv; acc[i * 4 + 2] = bv; acc[i * 4 + 3] = bv;
    }
#pragma unroll 4
    for (int c = 0; c < 64; ++c) {
        float4 xv = *(const float4*)&Xs[c * 64 + pt * 4];
        float4 wv = *(const float4*)&Ws[c * 64 + ot * 4];
        acc[0]  += wv.x * xv.x; acc[1]  += wv.x * xv.y; acc[2]  += wv.x * xv.z; acc[3]  += wv.x * xv.w;
        acc[4]  += wv.y * xv.x; acc[5]  += wv.y * xv.y; acc[6]  += wv.y * xv.z; acc[7]  += wv.y * xv.w;
        acc[8]  += wv.z * xv.x; acc[9]  += wv.z * xv.y; acc[10] += wv.z * xv.z; acc[11] += wv.z * xv.w;
        acc[12] += wv.w * xv.x; acc[13] += wv.w * xv.y; acc[14] += wv.w * xv.z; acc[15] += wv.w * xv.w;
    }
    float sA[4], sQ[4];
#pragma unroll
    for (int i = 0; i < 4; ++i) {
        int o = ot * 4 + i;
        ushort4 u;
        u.x = f2bf(acc[i * 4 + 0]); u.y = f2bf(acc[i * 4 + 1]);
        u.z = f2bf(acc[i * 4 + 2]); u.w = f2bf(acc[i * 4 + 3]);
        *(ushort4*)(y2 + (size_t)o * PTOT + p0 + pt * 4) = u;
        sA[i] = acc[i * 4] + acc[i * 4 + 1] + acc[i * 4 + 2] + acc[i * 4 + 3];
        sQ[i] = acc[i * 4] * acc[i * 4] + acc[i * 4 + 1] * acc[i * 4 + 1]
              + acc[i * 4 + 2] * acc[i * 4 + 2] + acc[i * 4 + 3] * acc[i * 4 + 3];
    }
#pragma unroll
    for (int off = 8; off >= 1; off >>= 1) {
#pragma unroll
        for (int i = 0; i < 4; ++i) {
            sA[i] += __shfl_down(sA[i], off);
            sQ[i] += __shfl_down(sQ[i], off);
        }
    }
    if ((tid & 15) == 0) {
#pragma unroll
        for (int i = 0; i < 4; ++i) { lsum[ot * 4 + i] = sA[i]; lsq[ot * 4 + i] = sQ[i]; }
    }
    __syncthreads();
    if (tid < 64) partial2[(size_t)blockIdx.x * 128 + tid] = lsum[tid];
    else if (tid < 128) partial2[(size_t)blockIdx.x * 128 + tid] = lsq[tid - 64];
}

// ---------- gram3: G3 = sum x3 x3^T, s3 = sum x3, x3 = relu(affine2(y2)) ----------
__global__ __launch_bounds__(256) void gram3_kernel(const unsigned short* __restrict__ y2,
                                                    const float* __restrict__ scale2,
                                                    const float* __restrict__ shift2,
                                                    float* __restrict__ G3,
                                                    float* __restrict__ s3) {
    __shared__ __align__(16) float Xst[64 * 68];   // [p][c], stride 68
    __shared__ float ssc[64], ssh[64];
    int tid = threadIdx.x;
    if (tid < 64) { ssc[tid] = scale2[tid]; ssh[tid] = shift2[tid]; }
    int r = tid >> 4, q = tid & 15;
    float g[16];
#pragma unroll
    for (int i = 0; i < 16; ++i) g[i] = 0.f;
    float srow[4] = {0.f, 0.f, 0.f, 0.f};
    int pbase = blockIdx.x * 2048;
    for (int tile = 0; tile < 32; ++tile) {
        __syncthreads();
        int pb = pbase + tile * 64;
        for (int i = tid * 4; i < 4096; i += 1024) {
            int c = i >> 6, p4 = i & 63;
            ushort4 u = *(const ushort4*)(y2 + (size_t)c * PTOT + pb + p4);
            float sc = ssc[c], sh = ssh[c];
            Xst[(p4 + 0) * 68 + c] = fmaxf(bf2f(u.x) * sc + sh, 0.f);
            Xst[(p4 + 1) * 68 + c] = fmaxf(bf2f(u.y) * sc + sh, 0.f);
            Xst[(p4 + 2) * 68 + c] = fmaxf(bf2f(u.z) * sc + sh, 0.f);
            Xst[(p4 + 3) * 68 + c] = fmaxf(bf2f(u.w) * sc + sh, 0.f);
        }
        __syncthreads();
#pragma unroll 4
        for (int p = 0; p < 64; ++p) {
            float4 av = *(const float4*)&Xst[p * 68 + r * 4];
            float4 bv = *(const float4*)&Xst[p * 68 + q * 4];
            g[0]  += av.x * bv.x; g[1]  += av.x * bv.y; g[2]  += av.x * bv.z; g[3]  += av.x * bv.w;
            g[4]  += av.y * bv.x; g[5]  += av.y * bv.y; g[6]  += av.y * bv.z; g[7]  += av.y * bv.w;
            g[8]  += av.z * bv.x; g[9]  += av.z * bv.y; g[10] += av.z * bv.z; g[11] += av.z * bv.w;
            g[12] += av.w * bv.x; g[13] += av.w * bv.y; g[14] += av.w * bv.z; g[15] += av.w * bv.w;
            if (q == 0) { srow[0] += av.x; srow[1] += av.y; srow[2] += av.z; srow[3] += av.w; }
        }
    }
#pragma unroll
    for (int i = 0; i < 4; ++i)
#pragma unroll
        for (int j = 0; j < 4; ++j)
            atomicAdd(&G3[(r * 4 + i) * 64 + q * 4 + j], g[i * 4 + j]);
    if (q == 0) {
#pragma unroll
        for (int i = 0; i < 4; ++i) atomicAdd(&s3[r * 4 + i], srow[i]);
    }
}

// ---------- finalize3: Gram -> scale3/shift3 ----------
__global__ __launch_bounds__(64) void finalize3_kernel(const float* __restrict__ G3,
                                                       const float* __restrict__ s3,
                                                       const float* __restrict__ w2,
                                                       const float* __restrict__ b2,
                                                       const float* __restrict__ gamma,
                                                       const float* __restrict__ beta,
                                                       float* __restrict__ scale,
                                                       float* __restrict__ shift) {
    int o = blockIdx.x * 64 + threadIdx.x;
    const float* wr = w2 + o * 64;
    double ws = 0.0;
    for (int c = 0; c < 64; ++c) ws += (double)wr[c] * (double)s3[c];
    double qf = 0.0;
    for (int i = 0; i < 64; ++i) {
        double ti = 0.0;
        for (int j = 0; j < 64; ++j) ti += (double)G3[i * 64 + j] * (double)wr[j];
        qf += (double)wr[i] * ti;
    }
    const double invP = 1.0 / (double)PTOT;
    double bb = (double)b2[o];
    double mean = ws * invP + bb;
    double ey2 = qf * invP + 2.0 * bb * (ws * invP) + bb * bb;
    double var = ey2 - mean * mean;
    float sc = gamma[o] / sqrtf((float)var + EPS_);
    scale[o] = sc;
    shift[o] = beta[o] - (float)mean * sc;
}

// ---------- conv3 + bn3 + relu + maxpool fused (tiled, bf16 y2 in) ----------
__global__ __launch_bounds__(256) void conv3_maxpool_kernel(const unsigned short* __restrict__ y2,
                                                            const float* __restrict__ w2t,  // [64c][128o]
                                                            const float* __restrict__ b2,
                                                            const float* __restrict__ scale2,
                                                            const float* __restrict__ shift2,
                                                            const float* __restrict__ scale3,
                                                            const float* __restrict__ shift3,
                                                            float* __restrict__ out1) {
    __shared__ float Xs[64 * 64];
    __shared__ float Ws[64 * 128];
    __shared__ float ssc2[64], ssh2[64];
    __shared__ float sb2[128], ssc3[128], ssh3[128];
    __shared__ float gmax[256];   // [2 groups][128 ch]
    int tid = threadIdx.x;
    int p0 = blockIdx.x * 64;
    if (tid < 64) { ssc2[tid] = scale2[tid]; ssh2[tid] = shift2[tid]; }
    for (int i = tid; i < 128; i += 256) { sb2[i] = b2[i]; ssc3[i] = scale3[i]; ssh3[i] = shift3[i]; }
    for (int i = tid; i < 8192; i += 256) Ws[i] = w2t[i];
    __syncthreads();
    for (int i = tid * 4; i < 4096; i += 1024) {
        int c = i >> 6, pp = i & 63;
        ushort4 u = *(const ushort4*)(y2 + (size_t)c * PTOT + p0 + pp);
        float sc = ssc2[c], sh = ssh2[c];
        float4 x;
        x.x = fmaxf(bf2f(u.x) * sc + sh, 0.f);
        x.y = fmaxf(bf2f(u.y) * sc + sh, 0.f);
        x.z = fmaxf(bf2f(u.z) * sc + sh, 0.f);
        x.w = fmaxf(bf2f(u.w) * sc + sh, 0.f);
        *(float4*)&Xs[i] = x;
    }
    int pt = tid & 15, ot = tid >> 4;
    float acc[32];
#pragma unroll
    for (int i = 0; i < 8; ++i) {
        float bv = sb2[ot * 8 + i];
        acc[i * 4 + 0] = bv; acc[i * 4 + 1] = bv; acc[i * 4 + 2] = bv; acc[i * 4 + 3] = bv;
    }
    __syncthreads();
#pragma unroll 4
    for (int c = 0; c < 64; ++c) {
        float4 xv = *(const float4*)&Xs[c * 64 + pt * 4];
#pragma unroll
        for (int i2 = 0; i2 < 2; ++i2) {
            float4 wv = *(const float4*)&Ws[c * 128 + ot * 8 + i2 * 4];
            float* a = &acc[i2 * 16];
            a[0]  += wv.x * xv.x; a[1]  += wv.x * xv.y; a[2]  += wv.x * xv.z; a[3]  += wv.x * xv.w;
            a[4]  += wv.y * xv.x; a[5]  += wv.y * xv.y; a[6]  += wv.y * xv.z; a[7]  += wv.y * xv.w;
            a[8]  += wv.z * xv.x; a[9]  += wv.z * xv.y; a[10] += wv.z * xv.z; a[11] += wv.z * xv.w;
            a[12] += wv.w * xv.x; a[13] += wv.w * xv.y; a[14] += wv.w * xv.z; a[15] += wv.w * xv.w;
        }
    }
    float mx[8];
#pragma unroll
    for (int i = 0; i < 8; ++i) {
        int o = ot * 8 + i;
        float sc = ssc3[o], sh = ssh3[o];
        float m = acc[i * 4 + 0] * sc + sh;
        m = fmaxf(m, acc[i * 4 + 1] * sc + sh);
        m = fmaxf(m, acc[i * 4 + 2] * sc + sh);
        m = fmaxf(m, acc[i * 4 + 3] * sc + sh);
        mx[i] = m;
    }
#pragma unroll
    for (int off = 4; off >= 1; off >>= 1)
#pragma unroll
        for (int i = 0; i < 8; ++i) mx[i] = fmaxf(mx[i], __shfl_down(mx[i], off));
    if ((pt & 7) == 0) {
        int gph = pt >> 3;
#pragma unroll
        for (int i = 0; i < 8; ++i) gmax[gph * 128 + ot * 8 + i] = fmaxf(mx[i], 0.f);
    }
    __syncthreads();
    int b = p0 >> 15, s0 = (p0 & 32767) >> 5;
    int o = tid >> 1, gph = tid & 1;
    out1[(size_t)b * 131072 + (size_t)o * 1024 + s0 + gph] = gmax[gph * 128 + o];
}

extern "C" void kernel_launch(void* const* d_in, const int* in_sizes, int n_in,
                              void* d_out, int out_size, void* d_ws, size_t ws_size,
                              hipStream_t stream) {
    (void)in_sizes; (void)n_in; (void)out_size; (void)ws_size;
    const float* xyz    = (const float*)d_in[0];
    const float* pts    = (const float*)d_in[1];
    const float* w0     = (const float*)d_in[2];
    const float* b0     = (const float*)d_in[3];
    const float* gamma0 = (const float*)d_in[4];
    const float* beta0  = (const float*)d_in[5];
    const float* w1     = (const float*)d_in[6];
    const float* b1     = (const float*)d_in[7];
    const float* gamma1 = (const float*)d_in[8];
    const float* beta1  = (const float*)d_in[9];
    const float* w2     = (const float*)d_in[10];
    const float* b2     = (const float*)d_in[11];
    const float* gamma2 = (const float*)d_in[12];
    const float* beta2  = (const float*)d_in[13];

    char* ws = (char*)d_ws;
    int*   ball_idx = (int*)(ws + 0);                       // 2 MB
    float* partial1 = (float*)(ws + 2097152);               // 1 MB (2048*128)
    float* partial2 = (float*)(ws + 3145728);               // 4 MB (8192*128)
    float* G3       = (float*)(ws + 7340032);               // 16 KB (+ s3 contiguous)
    float* s3       = (float*)(ws + 7356416);               // 256 B
    float* scsh     = (float*)(ws + 7357440);               // 2 KB
    float* w1t      = (float*)(ws + 7359488);               // 16 KB
    float* w2t      = (float*)(ws + 7375872);               // 32 KB
    unsigned short* y2 = (unsigned short*)(ws + 7408640);   // 64 MB -> total ~71.5 MB

    float* scale1 = scsh,       *shift1 = scsh + 64;
    float* scale2 = scsh + 128, *shift2 = scsh + 192;
    float* scale3 = scsh + 256, *shift3 = scsh + 384;

    float* out0 = (float*)d_out;                 // (B,3,NPOINT)
    float* out1 = out0 + B_ * 3 * NPOINT_;       // (B,128,NPOINT)

    hipLaunchKernelGGL(prep_kernel, dim3(32), dim3(256), 0, stream, w1, w2, w1t, w2t, G3);
    hipLaunchKernelGGL(fps_kernel, dim3(B_), dim3(256), 0, stream, xyz, out0);
    hipLaunchKernelGGL(ball_kernel, dim3(4096), dim3(256), 0, stream, xyz, out0, ball_idx);
    hipLaunchKernelGGL(conv1_stats_kernel, dim3(2048), dim3(256), 0, stream,
                       xyz, pts, out0, ball_idx, w0, b0, partial1);
    hipLaunchKernelGGL(reduce_finalize_kernel, dim3(64), dim3(256), 0, stream,
                       partial1, 2048, gamma0, beta0, scale1, shift1);
    hipLaunchKernelGGL(conv2_fused_kernel, dim3(8192), dim3(256), 0, stream,
                       xyz, pts, out0, ball_idx, w0, b0, w1t, b1, scale1, shift1, y2, partial2);
    hipLaunchKernelGGL(reduce_finalize_kernel, dim3(64), dim3(256), 0, stream,
                       partial2, 8192, gamma1, beta1, scale2, shift2);
    hipLaunchKernelGGL(gram3_kernel, dim3(256), dim3(256), 0, stream, y2, scale2, shift2, G3, s3);
    hipLaunchKernelGGL(finalize3_kernel, dim3(2), dim3(64), 0, stream,
                       G3, s3, w2, b2, gamma2, beta2, scale3, shift3);
    hipLaunchKernelGGL(conv3_maxpool_kernel, dim3(8192), dim3(256), 0, stream,
                       y2, w2t, b2, scale2, shift2, scale3, shift3, out1);
}

// Round 13
// 1423.860 us; speedup vs baseline: 15.5246x; 1.0538x over previous
//
#include <hip/hip_runtime.h>
#include <stdint.h>

#define B_ 16
#define N_ 4096
#define NPOINT_ 1024
#define NSAMPLE_ 32
#define PPB 32768            // NPOINT_*NSAMPLE_
#define PTOT 524288          // B_*PPB
#define EPS_ 1e-5f

// ---------- bf16 helpers ----------
__device__ __forceinline__ float bf2f(unsigned short h) {
    unsigned int u = ((unsigned int)h) << 16;
    float f; __builtin_memcpy(&f, &u, 4); return f;
}
__device__ __forceinline__ unsigned short f2bf(float f) {
    unsigned int u; __builtin_memcpy(&u, &f, 4);
    u = (u + 0x7fffu + ((u >> 16) & 1u)) >> 16;   // RNE
    return (unsigned short)u;
}

// ---------- prep: zero G3/s3, transpose w1,w2 ----------
__global__ __launch_bounds__(256) void prep_kernel(const float* __restrict__ w1,
                                                   const float* __restrict__ w2,
                                                   float* __restrict__ w1t,
                                                   float* __restrict__ w2t,
                                                   float* __restrict__ g3s3) {
    int i = blockIdx.x * 256 + threadIdx.x;   // 32 blocks -> 8192
    if (i < 4160) g3s3[i] = 0.f;
    if (i < 4096) { int o = i >> 6, c = i & 63; w1t[c * 64 + o] = w1[i]; }
    if (i < 8192) { int o = i >> 6, c = i & 63; w2t[c * 128 + o] = w2[i]; }
}

// ---------- FPS: fp32 FMA distances (bit-exact vs R10); DPP wave-argmax ----------
// In-wave 64-lane max of packed u64 (dist_bits<<32 | ~idx) via DPP
// row_shr:1/2/4/8 + row_bcast:15/31 (VALU latency, replaces 6 ds_permute ops),
// result read from lane 63 via readlane (SALU, wave-uniform).
#define DPP_U64_MAX(ctrl)                                                          \
    {                                                                              \
        unsigned int nh = (unsigned int)__builtin_amdgcn_update_dpp(               \
            (int)bh, (int)bh, ctrl, 0xF, 0xF, false);                              \
        unsigned int nl = (unsigned int)__builtin_amdgcn_update_dpp(               \
            (int)bl, (int)bl, ctrl, 0xF, 0xF, false);                              \
        bool gt = (nh > bh) || (nh == bh && nl > bl);                              \
        bh = gt ? nh : bh;                                                         \
        bl = gt ? nl : bl;                                                         \
    }

__global__ __launch_bounds__(256) void fps_kernel(const float* __restrict__ xyz,
                                                  float* __restrict__ out0) {
    const int b = blockIdx.x;
    const int tid = threadIdx.x;
    const int lane = tid & 63, wid = tid >> 6;
    __shared__ float sx[N_], sy[N_], sz[N_];
    __shared__ unsigned long long red[2][4];
    const float* xb = xyz + (size_t)b * 3 * N_;
    for (int p = tid; p < N_; p += 256) {
        sx[p] = xb[p]; sy[p] = xb[N_ + p]; sz[p] = xb[2 * N_ + p];
    }
    __syncthreads();
    float px[16], py[16], pz[16], md[16];
#pragma unroll
    for (int j = 0; j < 16; ++j) {
        int p = tid + j * 256;
        px[j] = sx[p]; py[j] = sy[p]; pz[j] = sz[p]; md[j] = 1e10f;
    }
    int cur = 0;
    for (int t = 0; t < NPOINT_; ++t) {
        if (tid == 0) {
            out0[(size_t)b * 3 * NPOINT_ + t]               = sx[cur];
            out0[(size_t)b * 3 * NPOINT_ + NPOINT_ + t]     = sy[cur];
            out0[(size_t)b * 3 * NPOINT_ + 2 * NPOINT_ + t] = sz[cur];
        }
        float cx = sx[cur], cy = sy[cur], cz = sz[cur];
        // j = 0 initializes (bv,bi); j>0 strict '>' keeps first (smallest) index
        float bv; int bi;
        {
            float dx = px[0] - cx, dy = py[0] - cy, dz = pz[0] - cz;
            float d = __builtin_fmaf(dz, dz, __builtin_fmaf(dy, dy, __fmul_rn(dx, dx)));
            float m = fminf(md[0], d);
            md[0] = m;
            bv = m; bi = tid;
        }
#pragma unroll
        for (int j = 1; j < 16; ++j) {
            float dx = px[j] - cx, dy = py[j] - cy, dz = pz[j] - cz;
            float d = __builtin_fmaf(dz, dz, __builtin_fmaf(dy, dy, __fmul_rn(dx, dx)));
            float m = fminf(md[j], d);
            md[j] = m;
            if (m > bv) { bv = m; bi = tid + j * 256; }
        }
        unsigned int bh; __builtin_memcpy(&bh, &bv, 4);   // dist >= 0 -> monotone bits
        unsigned int bl = ~(unsigned int)bi;              // larger ~idx == smaller idx
        DPP_U64_MAX(0x111)   // row_shr:1
        DPP_U64_MAX(0x112)   // row_shr:2
        DPP_U64_MAX(0x114)   // row_shr:4
        DPP_U64_MAX(0x118)   // row_shr:8
        DPP_U64_MAX(0x142)   // row_bcast:15
        DPP_U64_MAX(0x143)   // row_bcast:31
        unsigned int rh = (unsigned int)__builtin_amdgcn_readlane((int)bh, 63);
        unsigned int rl = (unsigned int)__builtin_amdgcn_readlane((int)bl, 63);
        if (lane == 0) red[t & 1][wid] = ((unsigned long long)rh << 32) | rl;
        __syncthreads();
        unsigned long long m0 = red[t & 1][0], m1 = red[t & 1][1];
        unsigned long long m2 = red[t & 1][2], m3 = red[t & 1][3];
        unsigned long long a = (m0 > m1) ? m0 : m1;
        unsigned long long c = (m2 > m3) ? m2 : m3;
        unsigned long long mm = (a > c) ? a : c;
        cur = (int)(~(unsigned int)mm) & (N_ - 1);
    }
}

// ---------- ball query: fp32 FMA-contracted (VERIFIED R10) ----------
__global__ __launch_bounds__(256) void ball_kernel(const float* __restrict__ xyz,
                                                   const float* __restrict__ out0,
                                                   int* __restrict__ ball_idx) {
    int gid  = (blockIdx.x * 256 + threadIdx.x) >> 6;
    int lane = threadIdx.x & 63;
    int b = gid >> 10, s = gid & 1023;
    const float* xb = xyz + (size_t)b * 3 * N_;
    float qx = out0[(size_t)b * 3 * NPOINT_ + s];
    float qy = out0[(size_t)b * 3 * NPOINT_ + NPOINT_ + s];
    float qz = out0[(size_t)b * 3 * NPOINT_ + 2 * NPOINT_ + s];
    float qs = __builtin_fmaf(qz, qz, __builtin_fmaf(qy, qy, __fmul_rn(qx, qx)));
    int cnt = 0, first = 0;
    int* outp = ball_idx + (size_t)gid * NSAMPLE_;
    for (int n0 = 0; n0 < N_; n0 += 64) {
        int n = n0 + lane;
        float px = xb[n], py = xb[N_ + n], pz = xb[2 * N_ + n];
        float dot = __builtin_fmaf(qz, pz, __builtin_fmaf(qy, py, __fmul_rn(qx, px)));
        float ps  = __builtin_fmaf(pz, pz, __builtin_fmaf(py, py, __fmul_rn(px, px)));
        float d   = __fadd_rn(__builtin_fmaf(-2.f, dot, qs), ps);
        bool ok = !(d > 0.04f);
        unsigned long long m = __ballot(ok);
        if (m) {
            if (cnt == 0) first = n0 + (__ffsll((unsigned long long)m) - 1);
            if (ok) {
                int r = __popcll(m & ((1ull << lane) - 1ull));
                int pos = cnt + r;
                if (pos < NSAMPLE_) outp[pos] = n;
            }
            cnt += __popcll(m);
            if (cnt >= NSAMPLE_) break;
        }
    }
    if (cnt < NSAMPLE_) {
        for (int pos = cnt + lane; pos < NSAMPLE_; pos += 64) outp[pos] = first;
    }
}

// ---------- conv1 stats: per-block partial sums of y1, y1^2 ----------
__global__ __launch_bounds__(256) void conv1_stats_kernel(const float* __restrict__ xyz,
                                                          const float* __restrict__ pts,
                                                          const float* __restrict__ out0,
                                                          const int* __restrict__ ball_idx,
                                                          const float* __restrict__ w0,
                                                          const float* __restrict__ b0,
                                                          float* __restrict__ partial1) {
    __shared__ float sw[448];
    __shared__ float lsum[256], lsq[256];
    int tid = threadIdx.x;
    int lane = tid & 63, wid = tid >> 6;
    for (int i = tid; i < 448; i += 256) sw[i] = (i < 384) ? w0[i] : b0[i - 384];
    __syncthreads();
    int p = blockIdx.x * 256 + tid;
    int b = p >> 15, s = (p & 32767) >> 5;
    int gi = ball_idx[p];
    const float* xb = xyz + (size_t)b * 3 * N_;
    const float* pb = pts + (size_t)b * 3 * N_;
    float x0 = xb[gi]          - out0[(size_t)b * 3 * NPOINT_ + s];
    float x1 = xb[N_ + gi]     - out0[(size_t)b * 3 * NPOINT_ + NPOINT_ + s];
    float x2 = xb[2 * N_ + gi] - out0[(size_t)b * 3 * NPOINT_ + 2 * NPOINT_ + s];
    float x3 = pb[gi], x4 = pb[N_ + gi], x5 = pb[2 * N_ + gi];
#pragma unroll
    for (int o = 0; o < 64; ++o) {
        float a = sw[384 + o];
        a += sw[o * 6 + 0] * x0; a += sw[o * 6 + 1] * x1; a += sw[o * 6 + 2] * x2;
        a += sw[o * 6 + 3] * x3; a += sw[o * 6 + 4] * x4; a += sw[o * 6 + 5] * x5;
        float v = a, v2 = a * a;
#pragma unroll
        for (int off = 32; off >= 1; off >>= 1) {
            v  += __shfl_down(v, off);
            v2 += __shfl_down(v2, off);
        }
        if (lane == 0) { lsum[wid * 64 + o] = v; lsq[wid * 64 + o] = v2; }
    }
    __syncthreads();
    if (tid < 64)
        partial1[(size_t)blockIdx.x * 128 + tid] =
            lsum[tid] + lsum[64 + tid] + lsum[128 + tid] + lsum[192 + tid];
    else if (tid < 128) {
        int c = tid - 64;
        partial1[(size_t)blockIdx.x * 128 + tid] =
            lsq[c] + lsq[64 + c] + lsq[128 + c] + lsq[192 + c];
    }
}

// ---------- reduce partials -> scale/shift ----------
__global__ __launch_bounds__(256) void reduce_finalize_kernel(const float* __restrict__ partials,
                                                              int nblocks,
                                                              const float* __restrict__ gamma,
                                                              const float* __restrict__ beta,
                                                              float* __restrict__ scale,
                                                              float* __restrict__ shift) {
    int c = blockIdx.x;
    int tid = threadIdx.x, lane = tid & 63, wid = tid >> 6;
    float s1 = 0.f, s2 = 0.f;
    for (int i = tid; i < nblocks; i += 256) {
        s1 += partials[(size_t)i * 128 + c];
        s2 += partials[(size_t)i * 128 + 64 + c];
    }
#pragma unroll
    for (int off = 32; off >= 1; off >>= 1) {
        s1 += __shfl_down(s1, off);
        s2 += __shfl_down(s2, off);
    }
    __shared__ float r1[4], r2[4];
    if (lane == 0) { r1[wid] = s1; r2[wid] = s2; }
    __syncthreads();
    if (tid == 0) {
        float S1 = r1[0] + r1[1] + r1[2] + r1[3];
        float S2 = r2[0] + r2[1] + r2[2] + r2[3];
        const float inv = 1.f / (float)PTOT;
        float m = S1 * inv;
        float v = S2 * inv - m * m;
        float sc = gamma[c] / sqrtf(v + EPS_);
        scale[c] = sc;
        shift[c] = beta[c] - m * sc;
    }
}

// ---------- conv2 fused: recompute conv1+bn1+relu, 64x64 GEMM, stats, store y2 bf16 ----------
__global__ __launch_bounds__(256) void conv2_fused_kernel(const float* __restrict__ xyz,
                                                          const float* __restrict__ pts,
                                                          const float* __restrict__ out0,
                                                          const int* __restrict__ ball_idx,
                                                          const float* __restrict__ w0,
                                                          const float* __restrict__ b0,
                                                          const float* __restrict__ w1t,  // [64c][64o]
                                                          const float* __restrict__ b1,
                                                          const float* __restrict__ scale1,
                                                          const float* __restrict__ shift1,
                                                          unsigned short* __restrict__ y2,
                                                          float* __restrict__ partial2) {
    __shared__ float sw0[448];
    __shared__ float x1s[6 * 64];
    __shared__ float Xs[64 * 64];
    __shared__ float Ws[64 * 64];
    __shared__ float ssc[64], ssh[64], sb1[64];
    __shared__ float lsum[64], lsq[64];
    int tid = threadIdx.x;
    int p0 = blockIdx.x * 64;
    for (int i = tid; i < 448; i += 256) sw0[i] = (i < 384) ? w0[i] : b0[i - 384];
    for (int i = tid; i < 4096; i += 256) Ws[i] = w1t[i];
    if (tid < 64) { ssc[tid] = scale1[tid]; ssh[tid] = shift1[tid]; sb1[tid] = b1[tid]; }
    if (tid < 64) {
        int p = p0 + tid;
        int b = p >> 15, s = (p & 32767) >> 5;
        int gi = ball_idx[p];
        const float* xb = xyz + (size_t)b * 3 * N_;
        const float* pb = pts + (size_t)b * 3 * N_;
        x1s[0 * 64 + tid] = xb[gi]          - out0[(size_t)b * 3 * NPOINT_ + s];
        x1s[1 * 64 + tid] = xb[N_ + gi]     - out0[(size_t)b * 3 * NPOINT_ + NPOINT_ + s];
        x1s[2 * 64 + tid] = xb[2 * N_ + gi] - out0[(size_t)b * 3 * NPOINT_ + 2 * NPOINT_ + s];
        x1s[3 * 64 + tid] = pb[gi];
        x1s[4 * 64 + tid] = pb[N_ + gi];
        x1s[5 * 64 + tid] = pb[2 * N_ + gi];
    }
    __syncthreads();
    for (int i = tid; i < 4096; i += 256) {
        int c = i >> 6, p = i & 63;
        float a = sw0[384 + c];
        a += sw0[c * 6 + 0] * x1s[p];
        a += sw0[c * 6 + 1] * x1s[64 + p];
        a += sw0[c * 6 + 2] * x1s[128 + p];
        a += sw0[c * 6 + 3] * x1s[192 + p];
        a += sw0[c * 6 + 4] * x1s[256 + p];
        a += sw0[c * 6 + 5] * x1s[320 + p];
        Xs[i] = fmaxf(a * ssc[c] + ssh[c], 0.f);
    }
    __syncthreads();
    int pt = tid & 15, ot = tid >> 4;
    float acc[16];
#pragma unroll
    for (int i = 0; i < 4; ++i) {
        float bv = sb1[ot * 4 + i];
        acc[i * 4 + 0] = bv; acc[i * 4 + 1] = bv; acc[i * 4 + 2] = bv; acc[i * 4 + 3] = bv;
    }
#pragma unroll 4
    for (int c = 0; c < 64; ++c) {
        float4 xv = *(const float4*)&Xs[c * 64 + pt * 4];
        float4 wv = *(const float4*)&Ws[c * 64 + ot * 4];
        acc[0]  += wv.x * xv.x; acc[1]  += wv.x * xv.y; acc[2]  += wv.x * xv.z; acc[3]  += wv.x * xv.w;
        acc[4]  += wv.y * xv.x; acc[5]  += wv.y * xv.y; acc[6]  += wv.y * xv.z; acc[7]  += wv.y * xv.w;
        acc[8]  += wv.z * xv.x; acc[9]  += wv.z * xv.y; acc[10] += wv.z * xv.z; acc[11] += wv.z * xv.w;
        acc[12] += wv.w * xv.x; acc[13] += wv.w * xv.y; acc[14] += wv.w * xv.z; acc[15] += wv.w * xv.w;
    }
    float sA[4], sQ[4];
#pragma unroll
    for (int i = 0; i < 4; ++i) {
        int o = ot * 4 + i;
        ushort4 u;
        u.x = f2bf(acc[i * 4 + 0]); u.y = f2bf(acc[i * 4 + 1]);
        u.z = f2bf(acc[i * 4 + 2]); u.w = f2bf(acc[i * 4 + 3]);
        *(ushort4*)(y2 + (size_t)o * PTOT + p0 + pt * 4) = u;
        sA[i] = acc[i * 4] + acc[i * 4 + 1] + acc[i * 4 + 2] + acc[i * 4 + 3];
        sQ[i] = acc[i * 4] * acc[i * 4] + acc[i * 4 + 1] * acc[i * 4 + 1]
              + acc[i * 4 + 2] * acc[i * 4 + 2] + acc[i * 4 + 3] * acc[i * 4 + 3];
    }
#pragma unroll
    for (int off = 8; off >= 1; off >>= 1) {
#pragma unroll
        for (int i = 0; i < 4; ++i) {
            sA[i] += __shfl_down(sA[i], off);
            sQ[i] += __shfl_down(sQ[i], off);
        }
    }
    if ((tid & 15) == 0) {
#pragma unroll
        for (int i = 0; i < 4; ++i) { lsum[ot * 4 + i] = sA[i]; lsq[ot * 4 + i] = sQ[i]; }
    }
    __syncthreads();
    if (tid < 64) partial2[(size_t)blockIdx.x * 128 + tid] = lsum[tid];
    else if (tid < 128) partial2[(size_t)blockIdx.x * 128 + tid] = lsq[tid - 64];
}

// ---------- gram3: G3 = sum x3 x3^T, s3 = sum x3, x3 = relu(affine2(y2)) ----------
__global__ __launch_bounds__(256) void gram3_kernel(const unsigned short* __restrict__ y2,
                                                    const float* __restrict__ scale2,
                                                    const float* __restrict__ shift2,
                                                    float* __restrict__ G3,
                                                    float* __restrict__ s3) {
    __shared__ __align__(16) float Xst[64 * 68];   // [p][c], stride 68
    __shared__ float ssc[64], ssh[64];
    int tid = threadIdx.x;
    if (tid < 64) { ssc[tid] = scale2[tid]; ssh[tid] = shift2[tid]; }
    int r = tid >> 4, q = tid & 15;
    float g[16];
#pragma unroll
    for (int i = 0; i < 16; ++i) g[i] = 0.f;
    float srow[4] = {0.f, 0.f, 0.f, 0.f};
    int pbase = blockIdx.x * 2048;
    for (int tile = 0; tile < 32; ++tile) {
        __syncthreads();
        int pb = pbase + tile * 64;
        for (int i = tid * 4; i < 4096; i += 1024) {
            int c = i >> 6, p4 = i & 63;
            ushort4 u = *(const ushort4*)(y2 + (size_t)c * PTOT + pb + p4);
            float sc = ssc[c], sh = ssh[c];
            Xst[(p4 + 0) * 68 + c] = fmaxf(bf2f(u.x) * sc + sh, 0.f);
            Xst[(p4 + 1) * 68 + c] = fmaxf(bf2f(u.y) * sc + sh, 0.f);
            Xst[(p4 + 2) * 68 + c] = fmaxf(bf2f(u.z) * sc + sh, 0.f);
            Xst[(p4 + 3) * 68 + c] = fmaxf(bf2f(u.w) * sc + sh, 0.f);
        }
        __syncthreads();
#pragma unroll 4
        for (int p = 0; p < 64; ++p) {
            float4 av = *(const float4*)&Xst[p * 68 + r * 4];
            float4 bv = *(const float4*)&Xst[p * 68 + q * 4];
            g[0]  += av.x * bv.x; g[1]  += av.x * bv.y; g[2]  += av.x * bv.z; g[3]  += av.x * bv.w;
            g[4]  += av.y * bv.x; g[5]  += av.y * bv.y; g[6]  += av.y * bv.z; g[7]  += av.y * bv.w;
            g[8]  += av.z * bv.x; g[9]  += av.z * bv.y; g[10] += av.z * bv.z; g[11] += av.z * bv.w;
            g[12] += av.w * bv.x; g[13] += av.w * bv.y; g[14] += av.w * bv.z; g[15] += av.w * bv.w;
            if (q == 0) { srow[0] += av.x; srow[1] += av.y; srow[2] += av.z; srow[3] += av.w; }
        }
    }
#pragma unroll
    for (int i = 0; i < 4; ++i)
#pragma unroll
        for (int j = 0; j < 4; ++j)
            atomicAdd(&G3[(r * 4 + i) * 64 + q * 4 + j], g[i * 4 + j]);
    if (q == 0) {
#pragma unroll
        for (int i = 0; i < 4; ++i) atomicAdd(&s3[r * 4 + i], srow[i]);
    }
}

// ---------- finalize3: Gram -> scale3/shift3 ----------
__global__ __launch_bounds__(64) void finalize3_kernel(const float* __restrict__ G3,
                                                       const float* __restrict__ s3,
                                                       const float* __restrict__ w2,
                                                       const float* __restrict__ b2,
                                                       const float* __restrict__ gamma,
                                                       const float* __restrict__ beta,
                                                       float* __restrict__ scale,
                                                       float* __restrict__ shift) {
    int o = blockIdx.x * 64 + threadIdx.x;
    const float* wr = w2 + o * 64;
    double ws = 0.0;
    for (int c = 0; c < 64; ++c) ws += (double)wr[c] * (double)s3[c];
    double qf = 0.0;
    for (int i = 0; i < 64; ++i) {
        double ti = 0.0;
        for (int j = 0; j < 64; ++j) ti += (double)G3[i * 64 + j] * (double)wr[j];
        qf += (double)wr[i] * ti;
    }
    const double invP = 1.0 / (double)PTOT;
    double bb = (double)b2[o];
    double mean = ws * invP + bb;
    double ey2 = qf * invP + 2.0 * bb * (ws * invP) + bb * bb;
    double var = ey2 - mean * mean;
    float sc = gamma[o] / sqrtf((float)var + EPS_);
    scale[o] = sc;
    shift[o] = beta[o] - (float)mean * sc;
}

// ---------- conv3 + bn3 + relu + maxpool fused (tiled, bf16 y2 in) ----------
__global__ __launch_bounds__(256) void conv3_maxpool_kernel(const unsigned short* __restrict__ y2,
                                                            const float* __restrict__ w2t,  // [64c][128o]
                                                            const float* __restrict__ b2,
                                                            const float* __restrict__ scale2,
                                                            const float* __restrict__ shift2,
                                                            const float* __restrict__ scale3,
                                                            const float* __restrict__ shift3,
                                                            float* __restrict__ out1) {
    __shared__ float Xs[64 * 64];
    __shared__ float Ws[64 * 128];
    __shared__ float ssc2[64], ssh2[64];
    __shared__ float sb2[128], ssc3[128], ssh3[128];
    __shared__ float gmax[256];   // [2 groups][128 ch]
    int tid = threadIdx.x;
    int p0 = blockIdx.x * 64;
    if (tid < 64) { ssc2[tid] = scale2[tid]; ssh2[tid] = shift2[tid]; }
    for (int i = tid; i < 128; i += 256) { sb2[i] = b2[i]; ssc3[i] = scale3[i]; ssh3[i] = shift3[i]; }
    for (int i = tid; i < 8192; i += 256) Ws[i] = w2t[i];
    __syncthreads();
    for (int i = tid * 4; i < 4096; i += 1024) {
        int c = i >> 6, pp = i & 63;
        ushort4 u = *(const ushort4*)(y2 + (size_t)c * PTOT + p0 + pp);
        float sc = ssc2[c], sh = ssh2[c];
        float4 x;
        x.x = fmaxf(bf2f(u.x) * sc + sh, 0.f);
        x.y = fmaxf(bf2f(u.y) * sc + sh, 0.f);
        x.z = fmaxf(bf2f(u.z) * sc + sh, 0.f);
        x.w = fmaxf(bf2f(u.w) * sc + sh, 0.f);
        *(float4*)&Xs[i] = x;
    }
    int pt = tid & 15, ot = tid >> 4;
    float acc[32];
#pragma unroll
    for (int i = 0; i < 8; ++i) {
        float bv = sb2[ot * 8 + i];
        acc[i * 4 + 0] = bv; acc[i * 4 + 1] = bv; acc[i * 4 + 2] = bv; acc[i * 4 + 3] = bv;
    }
    __syncthreads();
#pragma unroll 4
    for (int c = 0; c < 64; ++c) {
        float4 xv = *(const float4*)&Xs[c * 64 + pt * 4];
#pragma unroll
        for (int i2 = 0; i2 < 2; ++i2) {
            float4 wv = *(const float4*)&Ws[c * 128 + ot * 8 + i2 * 4];
            float* a = &acc[i2 * 16];
            a[0]  += wv.x * xv.x; a[1]  += wv.x * xv.y; a[2]  += wv.x * xv.z; a[3]  += wv.x * xv.w;
            a[4]  += wv.y * xv.x; a[5]  += wv.y * xv.y; a[6]  += wv.y * xv.z; a[7]  += wv.y * xv.w;
            a[8]  += wv.z * xv.x; a[9]  += wv.z * xv.y; a[10] += wv.z * xv.z; a[11] += wv.z * xv.w;
            a[12] += wv.w * xv.x; a[13] += wv.w * xv.y; a[14] += wv.w * xv.z; a[15] += wv.w * xv.w;
        }
    }
    float mx[8];
#pragma unroll
    for (int i = 0; i < 8; ++i) {
        int o = ot * 8 + i;
        float sc = ssc3[o], sh = ssh3[o];
        float m = acc[i * 4 + 0] * sc + sh;
        m = fmaxf(m, acc[i * 4 + 1] * sc + sh);
        m = fmaxf(m, acc[i * 4 + 2] * sc + sh);
        m = fmaxf(m, acc[i * 4 + 3] * sc + sh);
        mx[i] = m;
    }
#pragma unroll
    for (int off = 4; off >= 1; off >>= 1)
#pragma unroll
        for (int i = 0; i < 8; ++i) mx[i] = fmaxf(mx[i], __shfl_down(mx[i], off));
    if ((pt & 7) == 0) {
        int gph = pt >> 3;
#pragma unroll
        for (int i = 0; i < 8; ++i) gmax[gph * 128 + ot * 8 + i] = fmaxf(mx[i], 0.f);
    }
    __syncthreads();
    int b = p0 >> 15, s0 = (p0 & 32767) >> 5;
    int o = tid >> 1, gph = tid & 1;
    out1[(size_t)b * 131072 + (size_t)o * 1024 + s0 + gph] = gmax[gph * 128 + o];
}

extern "C" void kernel_launch(void* const* d_in, const int* in_sizes, int n_in,
                              void* d_out, int out_size, void* d_ws, size_t ws_size,
                              hipStream_t stream) {
    (void)in_sizes; (void)n_in; (void)out_size; (void)ws_size;
    const float* xyz    = (const float*)d_in[0];
    const float* pts    = (const float*)d_in[1];
    const float* w0     = (const float*)d_in[2];
    const float* b0     = (const float*)d_in[3];
    const float* gamma0 = (const float*)d_in[4];
    const float* beta0  = (const float*)d_in[5];
    const float* w1     = (const float*)d_in[6];
    const float* b1     = (const float*)d_in[7];
    const float* gamma1 = (const float*)d_in[8];
    const float* beta1  = (const float*)d_in[9];
    const float* w2     = (const float*)d_in[10];
    const float* b2     = (const float*)d_in[11];
    const float* gamma2 = (const float*)d_in[12];
    const float* beta2  = (const float*)d_in[13];

    char* ws = (char*)d_ws;
    int*   ball_idx = (int*)(ws + 0);                       // 2 MB
    float* partial1 = (float*)(ws + 2097152);               // 1 MB (2048*128)
    float* partial2 = (float*)(ws + 3145728);               // 4 MB (8192*128)
    float* G3       = (float*)(ws + 7340032);               // 16 KB (+ s3 contiguous)
    float* s3       = (float*)(ws + 7356416);               // 256 B
    float* scsh     = (float*)(ws + 7357440);               // 2 KB
    float* w1t      = (float*)(ws + 7359488);               // 16 KB
    float* w2t      = (float*)(ws + 7375872);               // 32 KB
    unsigned short* y2 = (unsigned short*)(ws + 7408640);   // 64 MB -> total ~71.5 MB

    float* scale1 = scsh,       *shift1 = scsh + 64;
    float* scale2 = scsh + 128, *shift2 = scsh + 192;
    float* scale3 = scsh + 256, *shift3 = scsh + 384;

    float* out0 = (float*)d_out;                 // (B,3,NPOINT)
    float* out1 = out0 + B_ * 3 * NPOINT_;       // (B,128,NPOINT)

    hipLaunchKernelGGL(prep_kernel, dim3(32), dim3(256), 0, stream, w1, w2, w1t, w2t, G3);
    hipLaunchKernelGGL(fps_kernel, dim3(B_), dim3(256), 0, stream, xyz, out0);
    hipLaunchKernelGGL(ball_kernel, dim3(4096), dim3(256), 0, stream, xyz, out0, ball_idx);
    hipLaunchKernelGGL(conv1_stats_kernel, dim3(2048), dim3(256), 0, stream,
                       xyz, pts, out0, ball_idx, w0, b0, partial1);
    hipLaunchKernelGGL(reduce_finalize_kernel, dim3(64), dim3(256), 0, stream,
                       partial1, 2048, gamma0, beta0, scale1, shift1);
    hipLaunchKernelGGL(conv2_fused_kernel, dim3(8192), dim3(256), 0, stream,
                       xyz, pts, out0, ball_idx, w0, b0, w1t, b1, scale1, shift1, y2, partial2);
    hipLaunchKernelGGL(reduce_finalize_kernel, dim3(64), dim3(256), 0, stream,
                       partial2, 8192, gamma1, beta1, scale2, shift2);
    hipLaunchKernelGGL(gram3_kernel, dim3(256), dim3(256), 0, stream, y2, scale2, shift2, G3, s3);
    hipLaunchKernelGGL(finalize3_kernel, dim3(2), dim3(64), 0, stream,
                       G3, s3, w2, b2, gamma2, beta2, scale3, shift3);
    hipLaunchKernelGGL(conv3_maxpool_kernel, dim3(8192), dim3(256), 0, stream,
                       y2, w2t, b2, scale2, shift2, scale3, shift3, out1);
}

// Round 14
// 1404.313 us; speedup vs baseline: 15.7407x; 1.0139x over previous
//
#include <hip/hip_runtime.h>
#include <stdint.h>

#define B_ 16
#define N_ 4096
#define NPOINT_ 1024
#define NSAMPLE_ 32
#define PPB 32768            // NPOINT_*NSAMPLE_
#define PTOT 524288          // B_*PPB
#define EPS_ 1e-5f

// ---------- bf16 helpers ----------
__device__ __forceinline__ float bf2f(unsigned short h) {
    unsigned int u = ((unsigned int)h) << 16;
    float f; __builtin_memcpy(&f, &u, 4); return f;
}
__device__ __forceinline__ unsigned short f2bf(float f) {
    unsigned int u; __builtin_memcpy(&u, &f, 4);
    u = (u + 0x7fffu + ((u >> 16) & 1u)) >> 16;   // RNE
    return (unsigned short)u;
}

// ---------- prep: zero G3/s3, transpose w1,w2 ----------
__global__ __launch_bounds__(256) void prep_kernel(const float* __restrict__ w1,
                                                   const float* __restrict__ w2,
                                                   float* __restrict__ w1t,
                                                   float* __restrict__ w2t,
                                                   float* __restrict__ g3s3) {
    int i = blockIdx.x * 256 + threadIdx.x;   // 32 blocks -> 8192
    if (i < 4160) g3s3[i] = 0.f;
    if (i < 4096) { int o = i >> 6, c = i & 63; w1t[c * 64 + o] = w1[i]; }
    if (i < 8192) { int o = i >> 6, c = i & 63; w2t[c * 128 + o] = w2[i]; }
}

// ---------- FPS: fp32 FMA distances (bit-exact vs R10); DPP wave-argmax ----------
// R14: NO global stores inside the iteration loop (the compiler's
// s_waitcnt vmcnt(0) before s_barrier put an HBM store-ack on every
// iteration's critical path). Selected indices go to an LDS list; out0 is
// written once in a coalesced epilogue.
#define DPP_U64_MAX(ctrl)                                                          \
    {                                                                              \
        unsigned int nh = (unsigned int)__builtin_amdgcn_update_dpp(               \
            (int)bh, (int)bh, ctrl, 0xF, 0xF, false);                              \
        unsigned int nl = (unsigned int)__builtin_amdgcn_update_dpp(               \
            (int)bl, (int)bl, ctrl, 0xF, 0xF, false);                              \
        bool gt = (nh > bh) || (nh == bh && nl > bl);                              \
        bh = gt ? nh : bh;                                                         \
        bl = gt ? nl : bl;                                                         \
    }

__global__ __launch_bounds__(256) void fps_kernel(const float* __restrict__ xyz,
                                                  float* __restrict__ out0) {
    const int b = blockIdx.x;
    const int tid = threadIdx.x;
    const int lane = tid & 63, wid = tid >> 6;
    __shared__ float sx[N_], sy[N_], sz[N_];
    __shared__ unsigned long long red[2][4];
    __shared__ int sidx[NPOINT_];
    const float* xb = xyz + (size_t)b * 3 * N_;
    for (int p = tid; p < N_; p += 256) {
        sx[p] = xb[p]; sy[p] = xb[N_ + p]; sz[p] = xb[2 * N_ + p];
    }
    __syncthreads();
    float px[16], py[16], pz[16], md[16];
#pragma unroll
    for (int j = 0; j < 16; ++j) {
        int p = tid + j * 256;
        px[j] = sx[p]; py[j] = sy[p]; pz[j] = sz[p]; md[j] = 1e10f;
    }
    int cur = 0;
    for (int t = 0; t < NPOINT_; ++t) {
        if (tid == 0) sidx[t] = cur;           // LDS only — no vmcnt on the loop
        float cx = sx[cur], cy = sy[cur], cz = sz[cur];
        // j = 0 initializes (bv,bi); j>0 strict '>' keeps first (smallest) index
        float bv; int bi;
        {
            float dx = px[0] - cx, dy = py[0] - cy, dz = pz[0] - cz;
            float d = __builtin_fmaf(dz, dz, __builtin_fmaf(dy, dy, __fmul_rn(dx, dx)));
            float m = fminf(md[0], d);
            md[0] = m;
            bv = m; bi = tid;
        }
#pragma unroll
        for (int j = 1; j < 16; ++j) {
            float dx = px[j] - cx, dy = py[j] - cy, dz = pz[j] - cz;
            float d = __builtin_fmaf(dz, dz, __builtin_fmaf(dy, dy, __fmul_rn(dx, dx)));
            float m = fminf(md[j], d);
            md[j] = m;
            if (m > bv) { bv = m; bi = tid + j * 256; }
        }
        unsigned int bh; __builtin_memcpy(&bh, &bv, 4);   // dist >= 0 -> monotone bits
        unsigned int bl = ~(unsigned int)bi;              // larger ~idx == smaller idx
        DPP_U64_MAX(0x111)   // row_shr:1
        DPP_U64_MAX(0x112)   // row_shr:2
        DPP_U64_MAX(0x114)   // row_shr:4
        DPP_U64_MAX(0x118)   // row_shr:8
        DPP_U64_MAX(0x142)   // row_bcast:15
        DPP_U64_MAX(0x143)   // row_bcast:31
        unsigned int rh = (unsigned int)__builtin_amdgcn_readlane((int)bh, 63);
        unsigned int rl = (unsigned int)__builtin_amdgcn_readlane((int)bl, 63);
        if (lane == 0) red[t & 1][wid] = ((unsigned long long)rh << 32) | rl;
        __syncthreads();
        unsigned long long m0 = red[t & 1][0], m1 = red[t & 1][1];
        unsigned long long m2 = red[t & 1][2], m3 = red[t & 1][3];
        unsigned long long a = (m0 > m1) ? m0 : m1;
        unsigned long long c = (m2 > m3) ? m2 : m3;
        unsigned long long mm = (a > c) ? a : c;
        cur = (int)(~(unsigned int)mm) & (N_ - 1);
    }
    __syncthreads();
    // coalesced epilogue: gather centers from LDS, store once
    for (int t = tid; t < NPOINT_; t += 256) {
        int ix = sidx[t];
        out0[(size_t)b * 3 * NPOINT_ + t]               = sx[ix];
        out0[(size_t)b * 3 * NPOINT_ + NPOINT_ + t]     = sy[ix];
        out0[(size_t)b * 3 * NPOINT_ + 2 * NPOINT_ + t] = sz[ix];
    }
}

// ---------- ball query: fp32 FMA-contracted (VERIFIED R10) ----------
__global__ __launch_bounds__(256) void ball_kernel(const float* __restrict__ xyz,
                                                   const float* __restrict__ out0,
                                                   int* __restrict__ ball_idx) {
    int gid  = (blockIdx.x * 256 + threadIdx.x) >> 6;
    int lane = threadIdx.x & 63;
    int b = gid >> 10, s = gid & 1023;
    const float* xb = xyz + (size_t)b * 3 * N_;
    float qx = out0[(size_t)b * 3 * NPOINT_ + s];
    float qy = out0[(size_t)b * 3 * NPOINT_ + NPOINT_ + s];
    float qz = out0[(size_t)b * 3 * NPOINT_ + 2 * NPOINT_ + s];
    float qs = __builtin_fmaf(qz, qz, __builtin_fmaf(qy, qy, __fmul_rn(qx, qx)));
    int cnt = 0, first = 0;
    int* outp = ball_idx + (size_t)gid * NSAMPLE_;
    for (int n0 = 0; n0 < N_; n0 += 64) {
        int n = n0 + lane;
        float px = xb[n], py = xb[N_ + n], pz = xb[2 * N_ + n];
        float dot = __builtin_fmaf(qz, pz, __builtin_fmaf(qy, py, __fmul_rn(qx, px)));
        float ps  = __builtin_fmaf(pz, pz, __builtin_fmaf(py, py, __fmul_rn(px, px)));
        float d   = __fadd_rn(__builtin_fmaf(-2.f, dot, qs), ps);
        bool ok = !(d > 0.04f);
        unsigned long long m = __ballot(ok);
        if (m) {
            if (cnt == 0) first = n0 + (__ffsll((unsigned long long)m) - 1);
            if (ok) {
                int r = __popcll(m & ((1ull << lane) - 1ull));
                int pos = cnt + r;
                if (pos < NSAMPLE_) outp[pos] = n;
            }
            cnt += __popcll(m);
            if (cnt >= NSAMPLE_) break;
        }
    }
    if (cnt < NSAMPLE_) {
        for (int pos = cnt + lane; pos < NSAMPLE_; pos += 64) outp[pos] = first;
    }
}

// ---------- conv1 stats: per-block partial sums of y1, y1^2 ----------
__global__ __launch_bounds__(256) void conv1_stats_kernel(const float* __restrict__ xyz,
                                                          const float* __restrict__ pts,
                                                          const float* __restrict__ out0,
                                                          const int* __restrict__ ball_idx,
                                                          const float* __restrict__ w0,
                                                          const float* __restrict__ b0,
                                                          float* __restrict__ partial1) {
    __shared__ float sw[448];
    __shared__ float lsum[256], lsq[256];
    int tid = threadIdx.x;
    int lane = tid & 63, wid = tid >> 6;
    for (int i = tid; i < 448; i += 256) sw[i] = (i < 384) ? w0[i] : b0[i - 384];
    __syncthreads();
    int p = blockIdx.x * 256 + tid;
    int b = p >> 15, s = (p & 32767) >> 5;
    int gi = ball_idx[p];
    const float* xb = xyz + (size_t)b * 3 * N_;
    const float* pb = pts + (size_t)b * 3 * N_;
    float x0 = xb[gi]          - out0[(size_t)b * 3 * NPOINT_ + s];
    float x1 = xb[N_ + gi]     - out0[(size_t)b * 3 * NPOINT_ + NPOINT_ + s];
    float x2 = xb[2 * N_ + gi] - out0[(size_t)b * 3 * NPOINT_ + 2 * NPOINT_ + s];
    float x3 = pb[gi], x4 = pb[N_ + gi], x5 = pb[2 * N_ + gi];
#pragma unroll
    for (int o = 0; o < 64; ++o) {
        float a = sw[384 + o];
        a += sw[o * 6 + 0] * x0; a += sw[o * 6 + 1] * x1; a += sw[o * 6 + 2] * x2;
        a += sw[o * 6 + 3] * x3; a += sw[o * 6 + 4] * x4; a += sw[o * 6 + 5] * x5;
        float v = a, v2 = a * a;
#pragma unroll
        for (int off = 32; off >= 1; off >>= 1) {
            v  += __shfl_down(v, off);
            v2 += __shfl_down(v2, off);
        }
        if (lane == 0) { lsum[wid * 64 + o] = v; lsq[wid * 64 + o] = v2; }
    }
    __syncthreads();
    if (tid < 64)
        partial1[(size_t)blockIdx.x * 128 + tid] =
            lsum[tid] + lsum[64 + tid] + lsum[128 + tid] + lsum[192 + tid];
    else if (tid < 128) {
        int c = tid - 64;
        partial1[(size_t)blockIdx.x * 128 + tid] =
            lsq[c] + lsq[64 + c] + lsq[128 + c] + lsq[192 + c];
    }
}

// ---------- reduce partials -> scale/shift ----------
__global__ __launch_bounds__(256) void reduce_finalize_kernel(const float* __restrict__ partials,
                                                              int nblocks,
                                                              const float* __restrict__ gamma,
                                                              const float* __restrict__ beta,
                                                              float* __restrict__ scale,
                                                              float* __restrict__ shift) {
    int c = blockIdx.x;
    int tid = threadIdx.x, lane = tid & 63, wid = tid >> 6;
    float s1 = 0.f, s2 = 0.f;
    for (int i = tid; i < nblocks; i += 256) {
        s1 += partials[(size_t)i * 128 + c];
        s2 += partials[(size_t)i * 128 + 64 + c];
    }
#pragma unroll
    for (int off = 32; off >= 1; off >>= 1) {
        s1 += __shfl_down(s1, off);
        s2 += __shfl_down(s2, off);
    }
    __shared__ float r1[4], r2[4];
    if (lane == 0) { r1[wid] = s1; r2[wid] = s2; }
    __syncthreads();
    if (tid == 0) {
        float S1 = r1[0] + r1[1] + r1[2] + r1[3];
        float S2 = r2[0] + r2[1] + r2[2] + r2[3];
        const float inv = 1.f / (float)PTOT;
        float m = S1 * inv;
        float v = S2 * inv - m * m;
        float sc = gamma[c] / sqrtf(v + EPS_);
        scale[c] = sc;
        shift[c] = beta[c] - m * sc;
    }
}

// ---------- conv2 fused: recompute conv1+bn1+relu, 64x64 GEMM, stats, store y2 bf16 ----------
__global__ __launch_bounds__(256) void conv2_fused_kernel(const float* __restrict__ xyz,
                                                          const float* __restrict__ pts,
                                                          const float* __restrict__ out0,
                                                          const int* __restrict__ ball_idx,
                                                          const float* __restrict__ w0,
                                                          const float* __restrict__ b0,
                                                          const float* __restrict__ w1t,  // [64c][64o]
                                                          const float* __restrict__ b1,
                                                          const float* __restrict__ scale1,
                                                          const float* __restrict__ shift1,
                                                          unsigned short* __restrict__ y2,
                                                          float* __restrict__ partial2) {
    __shared__ float sw0[448];
    __shared__ float x1s[6 * 64];
    __shared__ float Xs[64 * 64];
    __shared__ float Ws[64 * 64];
    __shared__ float ssc[64], ssh[64], sb1[64];
    __shared__ float lsum[64], lsq[64];
    int tid = threadIdx.x;
    int p0 = blockIdx.x * 64;
    for (int i = tid; i < 448; i += 256) sw0[i] = (i < 384) ? w0[i] : b0[i - 384];
    for (int i = tid; i < 4096; i += 256) Ws[i] = w1t[i];
    if (tid < 64) { ssc[tid] = scale1[tid]; ssh[tid] = shift1[tid]; sb1[tid] = b1[tid]; }
    if (tid < 64) {
        int p = p0 + tid;
        int b = p >> 15, s = (p & 32767) >> 5;
        int gi = ball_idx[p];
        const float* xb = xyz + (size_t)b * 3 * N_;
        const float* pb = pts + (size_t)b * 3 * N_;
        x1s[0 * 64 + tid] = xb[gi]          - out0[(size_t)b * 3 * NPOINT_ + s];
        x1s[1 * 64 + tid] = xb[N_ + gi]     - out0[(size_t)b * 3 * NPOINT_ + NPOINT_ + s];
        x1s[2 * 64 + tid] = xb[2 * N_ + gi] - out0[(size_t)b * 3 * NPOINT_ + 2 * NPOINT_ + s];
        x1s[3 * 64 + tid] = pb[gi];
        x1s[4 * 64 + tid] = pb[N_ + gi];
        x1s[5 * 64 + tid] = pb[2 * N_ + gi];
    }
    __syncthreads();
    for (int i = tid; i < 4096; i += 256) {
        int c = i >> 6, p = i & 63;
        float a = sw0[384 + c];
        a += sw0[c * 6 + 0] * x1s[p];
        a += sw0[c * 6 + 1] * x1s[64 + p];
        a += sw0[c * 6 + 2] * x1s[128 + p];
        a += sw0[c * 6 + 3] * x1s[192 + p];
        a += sw0[c * 6 + 4] * x1s[256 + p];
        a += sw0[c * 6 + 5] * x1s[320 + p];
        Xs[i] = fmaxf(a * ssc[c] + ssh[c], 0.f);
    }
    __syncthreads();
    int pt = tid & 15, ot = tid >> 4;
    float acc[16];
#pragma unroll
    for (int i = 0; i < 4; ++i) {
        float bv = sb1[ot * 4 + i];
        acc[i * 4 + 0] = bv; acc[i * 4 + 1] = bv; acc[i * 4 + 2] = bv; acc[i * 4 + 3] = bv;
    }
#pragma unroll 4
    for (int c = 0; c < 64; ++c) {
        float4 xv = *(const float4*)&Xs[c * 64 + pt * 4];
        float4 wv = *(const float4*)&Ws[c * 64 + ot * 4];
        acc[0]  += wv.x * xv.x; acc[1]  += wv.x * xv.y; acc[2]  += wv.x * xv.z; acc[3]  += wv.x * xv.w;
        acc[4]  += wv.y * xv.x; acc[5]  += wv.y * xv.y; acc[6]  += wv.y * xv.z; acc[7]  += wv.y * xv.w;
        acc[8]  += wv.z * xv.x; acc[9]  += wv.z * xv.y; acc[10] += wv.z * xv.z; acc[11] += wv.z * xv.w;
        acc[12] += wv.w * xv.x; acc[13] += wv.w * xv.y; acc[14] += wv.w * xv.z; acc[15] += wv.w * xv.w;
    }
    float sA[4], sQ[4];
#pragma unroll
    for (int i = 0; i < 4; ++i) {
        int o = ot * 4 + i;
        ushort4 u;
        u.x = f2bf(acc[i * 4 + 0]); u.y = f2bf(acc[i * 4 + 1]);
        u.z = f2bf(acc[i * 4 + 2]); u.w = f2bf(acc[i * 4 + 3]);
        *(ushort4*)(y2 + (size_t)o * PTOT + p0 + pt * 4) = u;
        sA[i] = acc[i * 4] + acc[i * 4 + 1] + acc[i * 4 + 2] + acc[i * 4 + 3];
        sQ[i] = acc[i * 4] * acc[i * 4] + acc[i * 4 + 1] * acc[i * 4 + 1]
              + acc[i * 4 + 2] * acc[i * 4 + 2] + acc[i * 4 + 3] * acc[i * 4 + 3];
    }
#pragma unroll
    for (int off = 8; off >= 1; off >>= 1) {
#pragma unroll
        for (int i = 0; i < 4; ++i) {
            sA[i] += __shfl_down(sA[i], off);
            sQ[i] += __shfl_down(sQ[i], off);
        }
    }
    if ((tid & 15) == 0) {
#pragma unroll
        for (int i = 0; i < 4; ++i) { lsum[ot * 4 + i] = sA[i]; lsq[ot * 4 + i] = sQ[i]; }
    }
    __syncthreads();
    if (tid < 64) partial2[(size_t)blockIdx.x * 128 + tid] = lsum[tid];
    else if (tid < 128) partial2[(size_t)blockIdx.x * 128 + tid] = lsq[tid - 64];
}

// ---------- gram3: G3 = sum x3 x3^T, s3 = sum x3, x3 = relu(affine2(y2)) ----------
__global__ __launch_bounds__(256) void gram3_kernel(const unsigned short* __restrict__ y2,
                                                    const float* __restrict__ scale2,
                                                    const float* __restrict__ shift2,
                                                    float* __restrict__ G3,
                                                    float* __restrict__ s3) {
    __shared__ __align__(16) float Xst[64 * 68];   // [p][c], stride 68
    __shared__ float ssc[64], ssh[64];
    int tid = threadIdx.x;
    if (tid < 64) { ssc[tid] = scale2[tid]; ssh[tid] = shift2[tid]; }
    int r = tid >> 4, q = tid & 15;
    float g[16];
#pragma unroll
    for (int i = 0; i < 16; ++i) g[i] = 0.f;
    float srow[4] = {0.f, 0.f, 0.f, 0.f};
    int pbase = blockIdx.x * 2048;
    for (int tile = 0; tile < 32; ++tile) {
        __syncthreads();
        int pb = pbase + tile * 64;
        for (int i = tid * 4; i < 4096; i += 1024) {
            int c = i >> 6, p4 = i & 63;
            ushort4 u = *(const ushort4*)(y2 + (size_t)c * PTOT + pb + p4);
            float sc = ssc[c], sh = ssh[c];
            Xst[(p4 + 0) * 68 + c] = fmaxf(bf2f(u.x) * sc + sh, 0.f);
            Xst[(p4 + 1) * 68 + c] = fmaxf(bf2f(u.y) * sc + sh, 0.f);
            Xst[(p4 + 2) * 68 + c] = fmaxf(bf2f(u.z) * sc + sh, 0.f);
            Xst[(p4 + 3) * 68 + c] = fmaxf(bf2f(u.w) * sc + sh, 0.f);
        }
        __syncthreads();
#pragma unroll 4
        for (int p = 0; p < 64; ++p) {
            float4 av = *(const float4*)&Xst[p * 68 + r * 4];
            float4 bv = *(const float4*)&Xst[p * 68 + q * 4];
            g[0]  += av.x * bv.x; g[1]  += av.x * bv.y; g[2]  += av.x * bv.z; g[3]  += av.x * bv.w;
            g[4]  += av.y * bv.x; g[5]  += av.y * bv.y; g[6]  += av.y * bv.z; g[7]  += av.y * bv.w;
            g[8]  += av.z * bv.x; g[9]  += av.z * bv.y; g[10] += av.z * bv.z; g[11] += av.z * bv.w;
            g[12] += av.w * bv.x; g[13] += av.w * bv.y; g[14] += av.w * bv.z; g[15] += av.w * bv.w;
            if (q == 0) { srow[0] += av.x; srow[1] += av.y; srow[2] += av.z; srow[3] += av.w; }
        }
    }
#pragma unroll
    for (int i = 0; i < 4; ++i)
#pragma unroll
        for (int j = 0; j < 4; ++j)
            atomicAdd(&G3[(r * 4 + i) * 64 + q * 4 + j], g[i * 4 + j]);
    if (q == 0) {
#pragma unroll
        for (int i = 0; i < 4; ++i) atomicAdd(&s3[r * 4 + i], srow[i]);
    }
}

// ---------- finalize3: Gram -> scale3/shift3 ----------
__global__ __launch_bounds__(64) void finalize3_kernel(const float* __restrict__ G3,
                                                       const float* __restrict__ s3,
                                                       const float* __restrict__ w2,
                                                       const float* __restrict__ b2,
                                                       const float* __restrict__ gamma,
                                                       const float* __restrict__ beta,
                                                       float* __restrict__ scale,
                                                       float* __restrict__ shift) {
    int o = blockIdx.x * 64 + threadIdx.x;
    const float* wr = w2 + o * 64;
    double ws = 0.0;
    for (int c = 0; c < 64; ++c) ws += (double)wr[c] * (double)s3[c];
    double qf = 0.0;
    for (int i = 0; i < 64; ++i) {
        double ti = 0.0;
        for (int j = 0; j < 64; ++j) ti += (double)G3[i * 64 + j] * (double)wr[j];
        qf += (double)wr[i] * ti;
    }
    const double invP = 1.0 / (double)PTOT;
    double bb = (double)b2[o];
    double mean = ws * invP + bb;
    double ey2 = qf * invP + 2.0 * bb * (ws * invP) + bb * bb;
    double var = ey2 - mean * mean;
    float sc = gamma[o] / sqrtf((float)var + EPS_);
    scale[o] = sc;
    shift[o] = beta[o] - (float)mean * sc;
}

// ---------- conv3 + bn3 + relu + maxpool fused (tiled, bf16 y2 in) ----------
__global__ __launch_bounds__(256) void conv3_maxpool_kernel(const unsigned short* __restrict__ y2,
                                                            const float* __restrict__ w2t,  // [64c][128o]
                                                            const float* __restrict__ b2,
                                                            const float* __restrict__ scale2,
                                                            const float* __restrict__ shift2,
                                                            const float* __restrict__ scale3,
                                                            const float* __restrict__ shift3,
                                                            float* __restrict__ out1) {
    __shared__ float Xs[64 * 64];
    __shared__ float Ws[64 * 128];
    __shared__ float ssc2[64], ssh2[64];
    __shared__ float sb2[128], ssc3[128], ssh3[128];
    __shared__ float gmax[256];   // [2 groups][128 ch]
    int tid = threadIdx.x;
    int p0 = blockIdx.x * 64;
    if (tid < 64) { ssc2[tid] = scale2[tid]; ssh2[tid] = shift2[tid]; }
    for (int i = tid; i < 128; i += 256) { sb2[i] = b2[i]; ssc3[i] = scale3[i]; ssh3[i] = shift3[i]; }
    for (int i = tid; i < 8192; i += 256) Ws[i] = w2t[i];
    __syncthreads();
    for (int i = tid * 4; i < 4096; i += 1024) {
        int c = i >> 6, pp = i & 63;
        ushort4 u = *(const ushort4*)(y2 + (size_t)c * PTOT + p0 + pp);
        float sc = ssc2[c], sh = ssh2[c];
        float4 x;
        x.x = fmaxf(bf2f(u.x) * sc + sh, 0.f);
        x.y = fmaxf(bf2f(u.y) * sc + sh, 0.f);
        x.z = fmaxf(bf2f(u.z) * sc + sh, 0.f);
        x.w = fmaxf(bf2f(u.w) * sc + sh, 0.f);
        *(float4*)&Xs[i] = x;
    }
    int pt = tid & 15, ot = tid >> 4;
    float acc[32];
#pragma unroll
    for (int i = 0; i < 8; ++i) {
        float bv = sb2[ot * 8 + i];
        acc[i * 4 + 0] = bv; acc[i * 4 + 1] = bv; acc[i * 4 + 2] = bv; acc[i * 4 + 3] = bv;
    }
    __syncthreads();
#pragma unroll 4
    for (int c = 0; c < 64; ++c) {
        float4 xv = *(const float4*)&Xs[c * 64 + pt * 4];
#pragma unroll
        for (int i2 = 0; i2 < 2; ++i2) {
            float4 wv = *(const float4*)&Ws[c * 128 + ot * 8 + i2 * 4];
            float* a = &acc[i2 * 16];
            a[0]  += wv.x * xv.x; a[1]  += wv.x * xv.y; a[2]  += wv.x * xv.z; a[3]  += wv.x * xv.w;
            a[4]  += wv.y * xv.x; a[5]  += wv.y * xv.y; a[6]  += wv.y * xv.z; a[7]  += wv.y * xv.w;
            a[8]  += wv.z * xv.x; a[9]  += wv.z * xv.y; a[10] += wv.z * xv.z; a[11] += wv.z * xv.w;
            a[12] += wv.w * xv.x; a[13] += wv.w * xv.y; a[14] += wv.w * xv.z; a[15] += wv.w * xv.w;
        }
    }
    float mx[8];
#pragma unroll
    for (int i = 0; i < 8; ++i) {
        int o = ot * 8 + i;
        float sc = ssc3[o], sh = ssh3[o];
        float m = acc[i * 4 + 0] * sc + sh;
        m = fmaxf(m, acc[i * 4 + 1] * sc + sh);
        m = fmaxf(m, acc[i * 4 + 2] * sc + sh);
        m = fmaxf(m, acc[i * 4 + 3] * sc + sh);
        mx[i] = m;
    }
#pragma unroll
    for (int off = 4; off >= 1; off >>= 1)
#pragma unroll
        for (int i = 0; i < 8; ++i) mx[i] = fmaxf(mx[i], __shfl_down(mx[i], off));
    if ((pt & 7) == 0) {
        int gph = pt >> 3;
#pragma unroll
        for (int i = 0; i < 8; ++i) gmax[gph * 128 + ot * 8 + i] = fmaxf(mx[i], 0.f);
    }
    __syncthreads();
    int b = p0 >> 15, s0 = (p0 & 32767) >> 5;
    int o = tid >> 1, gph = tid & 1;
    out1[(size_t)b * 131072 + (size_t)o * 1024 + s0 + gph] = gmax[gph * 128 + o];
}

extern "C" void kernel_launch(void* const* d_in, const int* in_sizes, int n_in,
                              void* d_out, int out_size, void* d_ws, size_t ws_size,
                              hipStream_t stream) {
    (void)in_sizes; (void)n_in; (void)out_size; (void)ws_size;
    const float* xyz    = (const float*)d_in[0];
    const float* pts    = (const float*)d_in[1];
    const float* w0     = (const float*)d_in[2];
    const float* b0     = (const float*)d_in[3];
    const float* gamma0 = (const float*)d_in[4];
    const float* beta0  = (const float*)d_in[5];
    const float* w1     = (const float*)d_in[6];
    const float* b1     = (const float*)d_in[7];
    const float* gamma1 = (const float*)d_in[8];
    const float* beta1  = (const float*)d_in[9];
    const float* w2     = (const float*)d_in[10];
    const float* b2     = (const float*)d_in[11];
    const float* gamma2 = (const float*)d_in[12];
    const float* beta2  = (const float*)d_in[13];

    char* ws = (char*)d_ws;
    int*   ball_idx = (int*)(ws + 0);                       // 2 MB
    float* partial1 = (float*)(ws + 2097152);               // 1 MB (2048*128)
    float* partial2 = (float*)(ws + 3145728);               // 4 MB (8192*128)
    float* G3       = (float*)(ws + 7340032);               // 16 KB (+ s3 contiguous)
    float* s3       = (float*)(ws + 7356416);               // 256 B
    float* scsh     = (float*)(ws + 7357440);               // 2 KB
    float* w1t      = (float*)(ws + 7359488);               // 16 KB
    float* w2t      = (float*)(ws + 7375872);               // 32 KB
    unsigned short* y2 = (unsigned short*)(ws + 7408640);   // 64 MB -> total ~71.5 MB

    float* scale1 = scsh,       *shift1 = scsh + 64;
    float* scale2 = scsh + 128, *shift2 = scsh + 192;
    float* scale3 = scsh + 256, *shift3 = scsh + 384;

    float* out0 = (float*)d_out;                 // (B,3,NPOINT)
    float* out1 = out0 + B_ * 3 * NPOINT_;       // (B,128,NPOINT)

    hipLaunchKernelGGL(prep_kernel, dim3(32), dim3(256), 0, stream, w1, w2, w1t, w2t, G3);
    hipLaunchKernelGGL(fps_kernel, dim3(B_), dim3(256), 0, stream, xyz, out0);
    hipLaunchKernelGGL(ball_kernel, dim3(4096), dim3(256), 0, stream, xyz, out0, ball_idx);
    hipLaunchKernelGGL(conv1_stats_kernel, dim3(2048), dim3(256), 0, stream,
                       xyz, pts, out0, ball_idx, w0, b0, partial1);
    hipLaunchKernelGGL(reduce_finalize_kernel, dim3(64), dim3(256), 0, stream,
                       partial1, 2048, gamma0, beta0, scale1, shift1);
    hipLaunchKernelGGL(conv2_fused_kernel, dim3(8192), dim3(256), 0, stream,
                       xyz, pts, out0, ball_idx, w0, b0, w1t, b1, scale1, shift1, y2, partial2);
    hipLaunchKernelGGL(reduce_finalize_kernel, dim3(64), dim3(256), 0, stream,
                       partial2, 8192, gamma1, beta1, scale2, shift2);
    hipLaunchKernelGGL(gram3_kernel, dim3(256), dim3(256), 0, stream, y2, scale2, shift2, G3, s3);
    hipLaunchKernelGGL(finalize3_kernel, dim3(2), dim3(64), 0, stream,
                       G3, s3, w2, b2, gamma2, beta2, scale3, shift3);
    hipLaunchKernelGGL(conv3_maxpool_kernel, dim3(8192), dim3(256), 0, stream,
                       y2, w2t, b2, scale2, shift2, scale3, shift3, out1);
}